// Round 6
// baseline (148.019 us; speedup 1.0000x reference)
//
#include <hip/hip_runtime.h>
#include <hip/hip_bf16.h>

#define S_DIM 1024
#define B_DIM 4
#define D_DIM 1024
#define H_DIM 16
#define DH    64
#define T_DIM (S_DIM * B_DIM)   // 4096
#define QKV_N (3 * D_DIM)       // 3072

using bf16 = __hip_bfloat16;
typedef __attribute__((ext_vector_type(4))) float fx4;
typedef __attribute__((ext_vector_type(8))) short bx8;

__device__ __forceinline__ unsigned short f2bf(float f) {
  union { float f; unsigned int u; } cv; cv.f = f;
  unsigned int u = cv.u;
  unsigned int r = (u + 0x7FFFu + ((u >> 16) & 1u)) >> 16;  // RNE
  return (unsigned short)r;
}

__device__ __forceinline__ void g2l16(const void* g, void* l) {
  __builtin_amdgcn_global_load_lds(
      (const __attribute__((address_space(1))) unsigned int*)g,
      (__attribute__((address_space(3))) unsigned int*)l, 16, 0, 0);
}

// ---------------- fused weight cast fp32 -> bf16 ----------------
__global__ __launch_bounds__(256) void cast2_f32_bf16(
    const float* __restrict__ a, bf16* __restrict__ da, int an4,
    const float* __restrict__ b, bf16* __restrict__ db, int bn4) {
  const int i = blockIdx.x * 256 + threadIdx.x;
  const float* src; bf16* dst; int j;
  if (i < an4) { src = a; dst = da; j = i; }
  else if (i < an4 + bn4) { src = b; dst = db; j = i - an4; }
  else return;
  const fx4 v = ((const fx4*)src)[j];
  ushort4 u;
  u.x = f2bf(v[0]); u.y = f2bf(v[1]); u.z = f2bf(v[2]); u.w = f2bf(v[3]);
  ((ushort4*)dst)[j] = u;
}

// ---------------- LN (row of 1024) -> bf16 ----------------
__global__ __launch_bounds__(256) void ln_bf16_kernel(
    const float* __restrict__ x, const float* __restrict__ w,
    const float* __restrict__ bb, bf16* __restrict__ out) {
  const int t = blockIdx.x, tid = threadIdx.x;
  const fx4 v = ((const fx4*)(x + (size_t)t * D_DIM))[tid];
  float s  = v[0] + v[1] + v[2] + v[3];
  float ss = v[0]*v[0] + v[1]*v[1] + v[2]*v[2] + v[3]*v[3];
#pragma unroll
  for (int off = 32; off >= 1; off >>= 1) {
    s  += __shfl_xor(s, off);
    ss += __shfl_xor(ss, off);
  }
  __shared__ float red[8];
  const int wid = tid >> 6, lane = tid & 63;
  if (lane == 0) { red[wid] = s; red[4 + wid] = ss; }
  __syncthreads();
  s  = red[0] + red[1] + red[2] + red[3];
  ss = red[4] + red[5] + red[6] + red[7];
  const float mu = s * (1.f / D_DIM);
  const float rstd = rsqrtf(ss * (1.f / D_DIM) - mu * mu + 1e-5f);
  const fx4 wv = ((const fx4*)w)[tid];
  const fx4 bv = ((const fx4*)bb)[tid];
  ushort4 u;
  u.x = f2bf((v[0] - mu) * rstd * wv[0] + bv[0]);
  u.y = f2bf((v[1] - mu) * rstd * wv[1] + bv[1]);
  u.z = f2bf((v[2] - mu) * rstd * wv[2] + bv[2]);
  u.w = f2bf((v[3] - mu) * rstd * wv[3] + bv[3]);
  ((ushort4*)(out + (size_t)t * D_DIM))[tid] = u;
}

// ---------------- qkv GEMM: 256x128 block, 4 waves, wave-tile 128x64 --------
// 42.7 FLOP per LDS byte (vs 32 balance) -> structurally MFMA-bound.
// kgroup-major LDS [4 kgrp][rows][16B]: linear g2l16 dest, per-lane source
// decode; frag reads stride 16B -> even bank spread (no conflicts).
// 2-phase: stage-next before compute, one vmcnt(0)+barrier per K-step.
// Epilogue: qkv split-write bf16; q pre-scaled 0.125*log2(e); v written
// [bh][s][64] (transposed later).
__global__ __launch_bounds__(256, 2) void gemm_qkv(
    const bf16* __restrict__ A, const bf16* __restrict__ B,
    const float* __restrict__ bias, ushort* __restrict__ qkvb, int N, int K) {
  __shared__ char sA[2][16384];   // [4 kgrp][256 row][16B]
  __shared__ char sB[2][8192];    // [4 kgrp][128 row][16B]
  const int tid  = threadIdx.x;
  const int brow = blockIdx.y * 256;
  const int bcol = blockIdx.x * 128;
  const int wid  = tid >> 6;
  const int lane = tid & 63;
  const int wr   = wid >> 1;
  const int wc   = wid & 1;
  const int fr   = lane & 15;
  const int fk   = lane >> 4;

  fx4 acc[8][4];
#pragma unroll
  for (int i = 0; i < 8; ++i)
#pragma unroll
    for (int j = 0; j < 4; ++j) acc[i][j] = 0.f;

  auto stage = [&](int buf, int kt) {
#pragma unroll
    for (int is = 0; is < 4; ++is) {   // A: 16KB
      const int o = is * 4096 + tid * 16;
      const int fkg = o >> 12;
      const int row = (o & 4095) >> 4;
      g2l16(A + (size_t)(brow + row) * K + kt + fkg * 8, sA[buf] + o);
    }
#pragma unroll
    for (int is = 0; is < 2; ++is) {   // B: 8KB
      const int o = is * 4096 + tid * 16;
      const int fkg = o >> 11;
      const int row = (o & 2047) >> 4;
      g2l16(B + (size_t)(bcol + row) * K + kt + fkg * 8, sB[buf] + o);
    }
  };

  stage(0, 0);
  asm volatile("s_waitcnt vmcnt(0)" ::: "memory");
  __builtin_amdgcn_s_barrier();
  asm volatile("" ::: "memory");

  const int nk = K >> 5;
  int cur = 0;
#pragma unroll 1
  for (int ki = 0; ki < nk; ++ki) {
    if (ki + 1 < nk) stage(cur ^ 1, (ki + 1) * 32);  // prefetch next K-slab
    asm volatile("" ::: "memory");

    bx8 af[8], bfr[4];
#pragma unroll
    for (int mm = 0; mm < 8; ++mm)
      af[mm] = *(const bx8*)(sA[cur] + fk * 4096 + (wr * 128 + mm * 16 + fr) * 16);
#pragma unroll
    for (int nn = 0; nn < 4; ++nn)
      bfr[nn] = *(const bx8*)(sB[cur] + fk * 2048 + (wc * 64 + nn * 16 + fr) * 16);
    __builtin_amdgcn_s_setprio(1);
#pragma unroll
    for (int mm = 0; mm < 8; ++mm)
#pragma unroll
      for (int nn = 0; nn < 4; ++nn)
        acc[mm][nn] = __builtin_amdgcn_mfma_f32_16x16x32_bf16(
            af[mm], bfr[nn], acc[mm][nn], 0, 0, 0);
    __builtin_amdgcn_s_setprio(0);

    if (ki + 1 < nk) {
      asm volatile("s_waitcnt vmcnt(0)" ::: "memory");
      __builtin_amdgcn_s_barrier();
      asm volatile("" ::: "memory");
    }
    cur ^= 1;
  }

  // C/D layout: col = lane&15, row = (lane>>4)*4 + reg
  const int row0 = brow + wr * 128 + fk * 4;
  const int col0 = bcol + wc * 64 + fr;
#pragma unroll
  for (int mm = 0; mm < 8; ++mm) {
#pragma unroll
    for (int nn = 0; nn < 4; ++nn) {
      const int col = col0 + nn * 16;
      const float bv = bias[col];
      const int which = col >> 10;          // 0=q 1=k 2=v
      const int rem   = col & 1023;
      const int hh    = rem >> 6;
      const int dh    = rem & 63;
      // q scaled by DH^-0.5 * log2(e): softmax runs in exp2 domain
      const float scale = (which == 0) ? 0.18033688f : 1.0f;
#pragma unroll
      for (int rr = 0; rr < 4; ++rr) {
        const int row = row0 + mm * 16 + rr;  // t = s*B + b
        const int ss2 = row >> 2, bb2 = row & 3;
        const float v = (acc[mm][nn][rr] + bv) * scale;
        qkvb[(size_t)which * 4194304 +
             ((size_t)(bb2 * 16 + hh)) * 65536 + (size_t)ss2 * 64 + dh] = f2bf(v);
      }
    }
  }
}

// ---------------- out-proj GEMM: 128x128, kgroup-major LDS, 2-phase ---------
// C(fp32) = acc + bias + resid.
__global__ __launch_bounds__(256, 2) void gemm_bt(
    const bf16* __restrict__ A, const bf16* __restrict__ B,
    const float* __restrict__ bias, const float* __restrict__ resid,
    float* __restrict__ C, int N, int K) {
  __shared__ char sA[2][8192];    // [4 kgrp][128 row][16B]
  __shared__ char sB[2][8192];
  const int tid  = threadIdx.x;
  const int brow = blockIdx.y * 128;
  const int bcol = blockIdx.x * 128;
  const int wid  = tid >> 6;
  const int lane = tid & 63;
  const int wr   = wid >> 1;
  const int wc   = wid & 1;
  const int fr   = lane & 15;
  const int fk   = lane >> 4;

  fx4 acc[4][4];
#pragma unroll
  for (int i = 0; i < 4; ++i)
#pragma unroll
    for (int j = 0; j < 4; ++j) acc[i][j] = 0.f;

  auto stage = [&](int buf, int kt) {
#pragma unroll
    for (int is = 0; is < 2; ++is) {
      const int o = is * 4096 + tid * 16;
      const int fkg = o >> 11;
      const int row = (o & 2047) >> 4;
      g2l16(A + (size_t)(brow + row) * K + kt + fkg * 8, sA[buf] + o);
      g2l16(B + (size_t)(bcol + row) * K + kt + fkg * 8, sB[buf] + o);
    }
  };

  stage(0, 0);
  asm volatile("s_waitcnt vmcnt(0)" ::: "memory");
  __builtin_amdgcn_s_barrier();
  asm volatile("" ::: "memory");

  const int nk = K >> 5;
  int cur = 0;
#pragma unroll 1
  for (int ki = 0; ki < nk; ++ki) {
    if (ki + 1 < nk) stage(cur ^ 1, (ki + 1) * 32);
    asm volatile("" ::: "memory");

    bx8 af[4], bfr[4];
#pragma unroll
    for (int mm = 0; mm < 4; ++mm)
      af[mm] = *(const bx8*)(sA[cur] + fk * 2048 + (wr * 64 + mm * 16 + fr) * 16);
#pragma unroll
    for (int nn = 0; nn < 4; ++nn)
      bfr[nn] = *(const bx8*)(sB[cur] + fk * 2048 + (wc * 64 + nn * 16 + fr) * 16);
#pragma unroll
    for (int mm = 0; mm < 4; ++mm)
#pragma unroll
      for (int nn = 0; nn < 4; ++nn)
        acc[mm][nn] = __builtin_amdgcn_mfma_f32_16x16x32_bf16(
            af[mm], bfr[nn], acc[mm][nn], 0, 0, 0);

    if (ki + 1 < nk) {
      asm volatile("s_waitcnt vmcnt(0)" ::: "memory");
      __builtin_amdgcn_s_barrier();
      asm volatile("" ::: "memory");
    }
    cur ^= 1;
  }

  const int row0 = brow + wr * 64 + fk * 4;
  const int col0 = bcol + wc * 64 + fr;
#pragma unroll
  for (int mm = 0; mm < 4; ++mm) {
#pragma unroll
    for (int nn = 0; nn < 4; ++nn) {
      const int col = col0 + nn * 16;
      const float bv = bias[col];
#pragma unroll
      for (int rr = 0; rr < 4; ++rr) {
        const int row = row0 + mm * 16 + rr;
        C[(size_t)row * N + col] = acc[mm][nn][rr] + bv + resid[(size_t)row * N + col];
      }
    }
  }
}

// ---------------- V [bh][s][64] -> V^T [bh][dh][1024] ----------------
__global__ __launch_bounds__(256) void transpose_v(
    const ushort* __restrict__ v, ushort* __restrict__ vt) {
  __shared__ ushort tile[64][65];
  const int g  = blockIdx.x;
  const int bh = g >> 4, st = g & 15;
  const int s0 = st * 64;
  const int tid = threadIdx.x;
  const int r  = tid >> 2;          // 0..63
  const int c0 = (tid & 3) * 16;    // 0,16,32,48
  const ushort* src = v + (size_t)bh * 65536 + (size_t)(s0 + r) * 64 + c0;
#pragma unroll
  for (int i = 0; i < 2; ++i) {
    const bx8 d = *(const bx8*)(src + i * 8);
#pragma unroll
    for (int j = 0; j < 8; ++j) tile[r][c0 + i * 8 + j] = (ushort)d[j];
  }
  __syncthreads();
  ushort* dst = vt + (size_t)bh * 65536 + (size_t)r * 1024 + s0 + c0;
  bx8 w0, w1;
#pragma unroll
  for (int j = 0; j < 8; ++j) {
    w0[j] = (short)tile[c0 + j][r];
    w1[j] = (short)tile[c0 + 8 + j][r];
  }
  *(bx8*)dst = w0;
  *(bx8*)(dst + 8) = w1;
}

// ---------------- MFMA flash attention ----------------
// One q-tile (64 rows) per block, grid 1024 = 4 blocks/CU. Big tiles first.
// Swapped S^T = mfma(K,Q); exp2-domain softmax; truncating bf16 P-pack;
// 2-phase pipelined LDS, defer-max, setprio.
__global__ __launch_bounds__(256, 4) void attn_mfma(
    const ushort* __restrict__ qb, const ushort* __restrict__ kb,
    const ushort* __restrict__ vtb, ushort* __restrict__ ob) {
  __shared__ __align__(16) char sK[2][8192];
  __shared__ __align__(16) char sVT[2][8192];
  __shared__ __align__(16) char sP[8192];
  const int tid  = threadIdx.x;
  const int wid  = tid >> 6;
  const int lane = tid & 63;
  const int g    = blockIdx.x;
  const int qt   = 15 - (g >> 6);   // descending work
  const int bh   = g & 63;
  const int b    = bh >> 4, h = bh & 15;
  const int fr   = lane & 15;
  const int fk   = lane >> 4;
  const size_t bhoff = (size_t)bh * 65536;
  char* const sPw = sP + wid * 2048;
  const int swp = (fr & 7) << 4;

  auto stage = [&](int buf, int k0) {
#pragma unroll
    for (int is = 0; is < 2; ++is) {
      const int L    = is * 4096 + tid * 16;
      const int row  = L >> 7;
      const int colb = (L & 127) ^ ((row & 7) << 4);
      g2l16(kb  + bhoff + (size_t)(k0 + row) * 64 + (colb >> 1), sK[buf]  + L);
      g2l16(vtb + bhoff + (size_t)row * 1024 + k0 + (colb >> 1), sVT[buf] + L);
    }
  };

  const int q0w = qt * 64 + wid * 16;
  const ushort* qp = qb + bhoff + (size_t)(q0w + fr) * 64;
  const bx8 qf0 = *(const bx8*)(qp + fk * 8);
  const bx8 qf1 = *(const bx8*)(qp + 32 + fk * 8);
  asm volatile("s_waitcnt vmcnt(0)" ::: "memory");

  fx4 o4[4];
  float m = -3e38f, l = 0.f;
#pragma unroll
  for (int dt = 0; dt < 4; ++dt) o4[dt] = 0.f;

  stage(0, 0);
  int cur = 0;

#pragma unroll 1
  for (int kbk = 0; kbk <= qt; ++kbk) {
    if (kbk < qt) {
      stage(cur ^ 1, (kbk + 1) * 64);
      asm volatile("s_waitcnt vmcnt(4)" ::: "memory");
    } else {
      asm volatile("s_waitcnt vmcnt(0)" ::: "memory");
    }
    __builtin_amdgcn_s_barrier();
    asm volatile("" ::: "memory");
    const char* sKc  = sK[cur];
    const char* sVTc = sVT[cur];

    fx4 s4[4];
    __builtin_amdgcn_s_setprio(1);
#pragma unroll
    for (int kt = 0; kt < 4; ++kt) {
      const int krow = kt * 16 + fr;
      const int sw   = (krow & 7) << 4;
      const bx8 kf0 = *(const bx8*)(sKc + krow * 128 + ((fk * 16) ^ sw));
      const bx8 kf1 = *(const bx8*)(sKc + krow * 128 + ((64 + fk * 16) ^ sw));
      fx4 z = {0.f, 0.f, 0.f, 0.f};
      z = __builtin_amdgcn_mfma_f32_16x16x32_bf16(kf0, qf0, z, 0, 0, 0);
      s4[kt] = __builtin_amdgcn_mfma_f32_16x16x32_bf16(kf1, qf1, z, 0, 0, 0);
    }
    __builtin_amdgcn_s_setprio(0);

    if (kbk == qt) {
      const int qloc = wid * 16 + fr;
#pragma unroll
      for (int kt = 0; kt < 4; ++kt) {
        const int keyb = kt * 16 + fk * 4;
#pragma unroll
        for (int rr = 0; rr < 4; ++rr)
          if (keyb + rr > qloc) s4[kt][rr] = -3e38f;
      }
    }

    float pm = s4[0][0];
#pragma unroll
    for (int kt = 0; kt < 4; ++kt)
#pragma unroll
      for (int rr = 0; rr < 4; ++rr) pm = fmaxf(pm, s4[kt][rr]);
    pm = fmaxf(pm, __shfl_xor(pm, 16));
    pm = fmaxf(pm, __shfl_xor(pm, 32));

    if (__any(pm > m + 11.5f)) {
      const float mn = fmaxf(m, pm);
      const float f  = exp2f(m - mn);
      m = mn;
      l *= f;
      float fq[4];
#pragma unroll
      for (int rr = 0; rr < 4; ++rr) fq[rr] = __shfl(f, fk * 4 + rr);
#pragma unroll
      for (int dt = 0; dt < 4; ++dt)
#pragma unroll
        for (int rr = 0; rr < 4; ++rr) o4[dt][rr] *= fq[rr];
    }

#pragma unroll
    for (int kt = 0; kt < 4; ++kt) {
      union { float f; unsigned u; } a0, a1, a2, a3;
      a0.f = exp2f(s4[kt][0] - m);
      a1.f = exp2f(s4[kt][1] - m);
      a2.f = exp2f(s4[kt][2] - m);
      a3.f = exp2f(s4[kt][3] - m);
      l += (a0.f + a1.f) + (a2.f + a3.f);
      uint2 pk;
      pk.x = (a0.u >> 16) | (a1.u & 0xFFFF0000u);
      pk.y = (a2.u >> 16) | (a3.u & 0xFFFF0000u);
      *(uint2*)(sPw + ((fr * 128 + kt * 32 + fk * 8) ^ swp)) = pk;
    }

    __builtin_amdgcn_s_setprio(1);
#pragma unroll
    for (int c = 0; c < 2; ++c) {
      const bx8 pa = *(const bx8*)(sPw + ((fr * 128 + c * 64 + fk * 16) ^ swp));
#pragma unroll
      for (int dt = 0; dt < 4; ++dt) {
        const int vrow = dt * 16 + fr;
        const bx8 vf = *(const bx8*)(sVTc + vrow * 128 +
                                     ((c * 64 + fk * 16) ^ ((vrow & 7) << 4)));
        o4[dt] = __builtin_amdgcn_mfma_f32_16x16x32_bf16(pa, vf, o4[dt], 0, 0, 0);
      }
    }
    __builtin_amdgcn_s_setprio(0);

    asm volatile("" ::: "memory");
    __builtin_amdgcn_s_barrier();
    asm volatile("" ::: "memory");
    cur ^= 1;
  }

  l += __shfl_xor(l, 16);
  l += __shfl_xor(l, 32);
  const float linv = 1.f / l;
  float lq[4];
#pragma unroll
  for (int rr = 0; rr < 4; ++rr) lq[rr] = __shfl(linv, fk * 4 + rr);

#pragma unroll
  for (int dt = 0; dt < 4; ++dt) {
#pragma unroll
    for (int rr = 0; rr < 4; ++rr) {
      const int qq = q0w + fk * 4 + rr;
      ob[((size_t)qq * 4 + b) * 1024 + h * 64 + dt * 16 + fr] =
          f2bf(o4[dt][rr] * lq[rr]);
    }
  }
}

// ---------------- LN2 + router + gate + final multiply ----------------
__global__ __launch_bounds__(256) void final_kernel(
    const float* __restrict__ xn, const float* __restrict__ w,
    const float* __restrict__ bb, const float* __restrict__ gw,
    float* __restrict__ out, float* __restrict__ rlog) {
  const int t = blockIdx.x, tid = threadIdx.x;
  const fx4 v = ((const fx4*)(xn + (size_t)t * D_DIM))[tid];
  float s  = v[0] + v[1] + v[2] + v[3];
  float ss = v[0]*v[0] + v[1]*v[1] + v[2]*v[2] + v[3]*v[3];
#pragma unroll
  for (int off = 32; off >= 1; off >>= 1) {
    s  += __shfl_xor(s, off);
    ss += __shfl_xor(ss, off);
  }
  __shared__ float red[8];
  __shared__ float red2[12];
  const int wid = tid >> 6, lane = tid & 63;
  if (lane == 0) { red[wid] = s; red[4 + wid] = ss; }
  __syncthreads();
  s  = red[0] + red[1] + red[2] + red[3];
  ss = red[4] + red[5] + red[6] + red[7];
  const float mu = s * (1.f / D_DIM);
  const float rstd = rsqrtf(ss * (1.f / D_DIM) - mu * mu + 1e-5f);
  const fx4 wv = ((const fx4*)w)[tid];
  const fx4 bv = ((const fx4*)bb)[tid];
  fx4 hv;
#pragma unroll
  for (int cc = 0; cc < 4; ++cc) hv[cc] = (v[cc] - mu) * rstd * wv[cc] + bv[cc];

  const fx4 w0 = ((const fx4*)(gw           ))[tid];
  const fx4 w1 = ((const fx4*)(gw +     D_DIM))[tid];
  const fx4 w2 = ((const fx4*)(gw + 2 * D_DIM))[tid];
  float g0 = hv[0]*w0[0] + hv[1]*w0[1] + hv[2]*w0[2] + hv[3]*w0[3];
  float g1 = hv[0]*w1[0] + hv[1]*w1[1] + hv[2]*w1[2] + hv[3]*w1[3];
  float g2 = hv[0]*w2[0] + hv[1]*w2[1] + hv[2]*w2[2] + hv[3]*w2[3];
#pragma unroll
  for (int off = 32; off >= 1; off >>= 1) {
    g0 += __shfl_xor(g0, off);
    g1 += __shfl_xor(g1, off);
    g2 += __shfl_xor(g2, off);
  }
  if (lane == 0) { red2[wid] = g0; red2[4 + wid] = g1; red2[8 + wid] = g2; }
  __syncthreads();
  g0 = red2[0] + red2[1] + red2[2]  + red2[3];
  g1 = red2[4] + red2[5] + red2[6]  + red2[7];
  g2 = red2[8] + red2[9] + red2[10] + red2[11];

  const float lmax = fmaxf(g0, fmaxf(g1, g2));
  const float lmin = fminf(g0, fminf(g1, g2));
  const float lmid = (g0 + g1 + g2) - lmax - lmin;
  const float gate = 1.f / (1.f + __expf(lmid - lmax));

  ((fx4*)(out + (size_t)t * D_DIM))[tid] = v * gate;
  if (tid == 0) {
    rlog[(size_t)t * 3 + 0] = g0;
    rlog[(size_t)t * 3 + 1] = g1;
    rlog[(size_t)t * 3 + 2] = g2;
  }
}

extern "C" void kernel_launch(void* const* d_in, const int* in_sizes, int n_in,
                              void* d_out, int out_size, void* d_ws, size_t ws_size,
                              hipStream_t stream) {
  (void)in_sizes; (void)n_in; (void)out_size; (void)ws_size;
  const float* x    = (const float*)d_in[0];
  const float* ln1w = (const float*)d_in[1];
  const float* ln1b = (const float*)d_in[2];
  const float* ln2w = (const float*)d_in[3];
  const float* ln2b = (const float*)d_in[4];
  const float* win  = (const float*)d_in[5];
  const float* bin  = (const float*)d_in[6];
  const float* wout = (const float*)d_in[7];
  const float* bout = (const float*)d_in[8];
  const float* gw   = (const float*)d_in[9];
  // fc_w / fc_b / proj_w / proj_b (d_in[10..13]) are dead code in the reference.

  char* ws = (char*)d_ws;
  bf16*   w_in_b  = (bf16*)(ws);               // 6 MiB
  bf16*   w_out_b = (bf16*)(ws + 6291456);     // 2 MiB
  bf16*   h_b     = (bf16*)(ws + 8388608);     // 8 MiB (LN1 out; o_b aliases)
  ushort* o_b     = (ushort*)h_b;              // alias: h dead after GEMM1
  ushort* qkvb    = (ushort*)(ws + 16777216);  // 24 MiB: q/k/v bf16 [bh][s][64]
  ushort* q_b     = qkvb;
  ushort* k_b     = qkvb + 4194304;
  ushort* v_b     = qkvb + 8388608;
  float*  xnew    = (float*)(ws + 41943040);   // 16 MiB
  ushort* vt_b    = (ushort*)(ws + 58720256);  // 8 MiB: V^T [bh][dh][s]
  // total ws use: 64 MiB

  float* out  = (float*)d_out;
  float* rlog = out + (size_t)T_DIM * D_DIM;

  cast2_f32_bf16<<<4096, 256, 0, stream>>>(win, w_in_b, 786432,
                                           wout, w_out_b, 262144);
  ln_bf16_kernel<<<T_DIM, 256, 0, stream>>>(x, ln1w, ln1b, h_b);
  gemm_qkv<<<dim3(QKV_N / 128, T_DIM / 256), 256, 0, stream>>>(
      h_b, w_in_b, bin, qkvb, QKV_N, D_DIM);
  transpose_v<<<1024, 256, 0, stream>>>(v_b, vt_b);
  attn_mfma<<<1024, 256, 0, stream>>>(q_b, k_b, vt_b, o_b);
  gemm_bt<<<dim3(D_DIM / 128, T_DIM / 128), 256, 0, stream>>>(
      (const bf16*)o_b, w_out_b, bout, x, xnew, D_DIM, D_DIM);
  final_kernel<<<T_DIM, 256, 0, stream>>>(xnew, ln2w, ln2b, gw, out, rlog);
}

// Round 7
// 123.398 us; speedup vs baseline: 1.1995x; 1.1995x over previous
//
#include <hip/hip_runtime.h>
#include <hip/hip_bf16.h>

#define S_DIM 1024
#define B_DIM 4
#define D_DIM 1024
#define H_DIM 16
#define DH    64
#define T_DIM (S_DIM * B_DIM)   // 4096
#define QKV_N (3 * D_DIM)       // 3072

using bf16 = __hip_bfloat16;
typedef __attribute__((ext_vector_type(4))) float fx4;
typedef __attribute__((ext_vector_type(8))) short bx8;

__device__ __forceinline__ unsigned short f2bf(float f) {
  union { float f; unsigned int u; } cv; cv.f = f;
  unsigned int u = cv.u;
  unsigned int r = (u + 0x7FFFu + ((u >> 16) & 1u)) >> 16;  // RNE
  return (unsigned short)r;
}

__device__ __forceinline__ void g2l16(const void* g, void* l) {
  __builtin_amdgcn_global_load_lds(
      (const __attribute__((address_space(1))) unsigned int*)g,
      (__attribute__((address_space(3))) unsigned int*)l, 16, 0, 0);
}

// ---------------- fused weight cast fp32 -> bf16 ----------------
__global__ __launch_bounds__(256) void cast2_f32_bf16(
    const float* __restrict__ a, bf16* __restrict__ da, int an4,
    const float* __restrict__ b, bf16* __restrict__ db, int bn4) {
  const int i = blockIdx.x * 256 + threadIdx.x;
  const float* src; bf16* dst; int j;
  if (i < an4) { src = a; dst = da; j = i; }
  else if (i < an4 + bn4) { src = b; dst = db; j = i - an4; }
  else return;
  const fx4 v = ((const fx4*)src)[j];
  ushort4 u;
  u.x = f2bf(v[0]); u.y = f2bf(v[1]); u.z = f2bf(v[2]); u.w = f2bf(v[3]);
  ((ushort4*)dst)[j] = u;
}

// ---------------- LN (row of 1024) -> bf16 ----------------
__global__ __launch_bounds__(256) void ln_bf16_kernel(
    const float* __restrict__ x, const float* __restrict__ w,
    const float* __restrict__ bb, bf16* __restrict__ out) {
  const int t = blockIdx.x, tid = threadIdx.x;
  const fx4 v = ((const fx4*)(x + (size_t)t * D_DIM))[tid];
  float s  = v[0] + v[1] + v[2] + v[3];
  float ss = v[0]*v[0] + v[1]*v[1] + v[2]*v[2] + v[3]*v[3];
#pragma unroll
  for (int off = 32; off >= 1; off >>= 1) {
    s  += __shfl_xor(s, off);
    ss += __shfl_xor(ss, off);
  }
  __shared__ float red[8];
  const int wid = tid >> 6, lane = tid & 63;
  if (lane == 0) { red[wid] = s; red[4 + wid] = ss; }
  __syncthreads();
  s  = red[0] + red[1] + red[2] + red[3];
  ss = red[4] + red[5] + red[6] + red[7];
  const float mu = s * (1.f / D_DIM);
  const float rstd = rsqrtf(ss * (1.f / D_DIM) - mu * mu + 1e-5f);
  const fx4 wv = ((const fx4*)w)[tid];
  const fx4 bv = ((const fx4*)bb)[tid];
  ushort4 u;
  u.x = f2bf((v[0] - mu) * rstd * wv[0] + bv[0]);
  u.y = f2bf((v[1] - mu) * rstd * wv[1] + bv[1]);
  u.z = f2bf((v[2] - mu) * rstd * wv[2] + bv[2]);
  u.w = f2bf((v[3] - mu) * rstd * wv[3] + bv[3]);
  ((ushort4*)(out + (size_t)t * D_DIM))[tid] = u;
}

// ---------------- qkv GEMM: 256x256, BK=64, 8 waves, phase-split ----------
// C[4096,3072] = A[4096,1024] @ B[3072,1024]^T, epilogue splits to q/k/v.
// LDS: row-major [256 rows][8 chunks of 16B] per operand per buffer, with
// chunk swizzle sc = c16 ^ (row&7). Staging keeps linear g2l16 dest; the
// source chunk is inverse-swizzled (per-row permutation -> full 128B line
// coalescing preserved). ds_read per 16-lane quarter: sc takes all 8 values
// twice -> 2-way bank aliasing = free.
// Pipeline ledger (per-thread loads, issue order per tile: B01,B23,A02,A13;
// stage unit u covers rows [64u,64u+64), 1 load/thread/unit):
//   P1: issue B01(t+1) [outst<=10]; vmcnt(4) -> B01,B23,A02(t) landed;
//       barrier; compute (h0,kk0) [A rows in units 0,2; B unit wc].
//   P2: issue B23(t+1) [<=6]; vmcnt(4) -> A13(t) landed; barrier;
//       compute (h1,kk0).
//   P3: issue A02(t+1) [<=6]; compute (h0,kk1) [same units as P1: landed].
//   P4: issue A13(t+1) [<=8]; compute (h1,kk1); barrier (readers of buf done
//       before t+1's stages overwrite it).
// vmcnt never drains to 0 in the main loop. Last tile peeled: vmcnt(2)/(0).
__global__ __launch_bounds__(512, 2) void gemm_qkv8(
    const bf16* __restrict__ A, const bf16* __restrict__ B,
    const float* __restrict__ bias, ushort* __restrict__ qkvb, int K) {
  __shared__ char sA[2][32768];
  __shared__ char sB[2][32768];
  const int tid  = threadIdx.x;              // 0..511
  const int bid  = blockIdx.x;               // 192 blocks, 24 per XCD
  const int swz  = (bid & 7) * 24 + (bid >> 3);
  const int bx   = swz % 12, by = swz / 12;
  const int brow = by * 256, bcol = bx * 256;
  const int wid  = tid >> 6;
  const int lane = tid & 63;
  const int wr   = wid >> 2;      // 0..1 (wave row: 128 rows)
  const int wc   = wid & 3;       // 0..3 (wave col: 64 cols)
  const int fr   = lane & 15;
  const int fk   = lane >> 4;

  fx4 acc[8][4];
#pragma unroll
  for (int i = 0; i < 8; ++i)
#pragma unroll
    for (int j = 0; j < 4; ++j) acc[i][j] = 0.f;

  // stage one 8KB unit (rows [64u,64u+64), all 64 k) with swizzled source
  auto stA = [&](int buf, int u, int kel) {
    const int row = u * 64 + (tid >> 3);
    const int c16 = (tid & 7) ^ (row & 7);
    g2l16(A + (size_t)(brow + row) * K + kel + c16 * 8,
          sA[buf] + u * 8192 + tid * 16);
  };
  auto stB = [&](int buf, int u, int kel) {
    const int row = u * 64 + (tid >> 3);
    const int c16 = (tid & 7) ^ (row & 7);
    g2l16(B + (size_t)(bcol + row) * K + kel + c16 * 8,
          sB[buf] + u * 8192 + tid * 16);
  };

  // one phase: 8 ds_read_b128 + 16 MFMA (C-quadrant h x all nn, k-slice kk)
  auto phase = [&](int buf, int h, int kk) {
    bx8 af[4], bfv[4];
#pragma unroll
    for (int mm = 0; mm < 4; ++mm) {
      const int arow = wr * 128 + (h * 4 + mm) * 16 + fr;
      af[mm] = *(const bx8*)(sA[buf] + arow * 128 +
                             (((4 * kk + fk) ^ (arow & 7)) * 16));
    }
#pragma unroll
    for (int nn = 0; nn < 4; ++nn) {
      const int brw = wc * 64 + nn * 16 + fr;
      bfv[nn] = *(const bx8*)(sB[buf] + brw * 128 +
                              (((4 * kk + fk) ^ (brw & 7)) * 16));
    }
    __builtin_amdgcn_s_setprio(1);
#pragma unroll
    for (int mm = 0; mm < 4; ++mm)
#pragma unroll
      for (int nn = 0; nn < 4; ++nn)
        acc[h * 4 + mm][nn] = __builtin_amdgcn_mfma_f32_16x16x32_bf16(
            af[mm], bfv[nn], acc[h * 4 + mm][nn], 0, 0, 0);
    __builtin_amdgcn_s_setprio(0);
  };

  // prologue: tile 0, same issue order as steady state
  stB(0, 0, 0); stB(0, 1, 0); stB(0, 2, 0); stB(0, 3, 0);
  stA(0, 0, 0); stA(0, 2, 0); stA(0, 1, 0); stA(0, 3, 0);

  const int nk = K >> 6;   // 16
#pragma unroll 1
  for (int t = 0; t < nk - 1; ++t) {
    const int buf = t & 1, nb = buf ^ 1;
    const int kn = (t + 1) << 6;
    // P1
    stB(nb, 0, kn); stB(nb, 1, kn);
    asm volatile("s_waitcnt vmcnt(4)" ::: "memory");
    __builtin_amdgcn_s_barrier();
    phase(buf, 0, 0);
    // P2
    stB(nb, 2, kn); stB(nb, 3, kn);
    asm volatile("s_waitcnt vmcnt(4)" ::: "memory");
    __builtin_amdgcn_s_barrier();
    phase(buf, 1, 0);
    // P3
    stA(nb, 0, kn); stA(nb, 2, kn);
    phase(buf, 0, 1);
    // P4
    stA(nb, 1, kn); stA(nb, 3, kn);
    phase(buf, 1, 1);
    __builtin_amdgcn_s_barrier();   // buf readers done before t+1 overwrites
  }
  {  // peeled last tile
    const int buf = (nk - 1) & 1;
    asm volatile("s_waitcnt vmcnt(2)" ::: "memory");  // B01,B23,A02 landed
    __builtin_amdgcn_s_barrier();
    phase(buf, 0, 0);
    asm volatile("s_waitcnt vmcnt(0)" ::: "memory");  // A13 landed
    __builtin_amdgcn_s_barrier();
    phase(buf, 1, 0);
    phase(buf, 0, 1);
    phase(buf, 1, 1);
  }

  // epilogue: C/D layout col = lane&15, row = (lane>>4)*4 + reg
  const int row0 = brow + wr * 128 + fk * 4;
  const int col0 = bcol + wc * 64 + fr;
#pragma unroll
  for (int mm = 0; mm < 8; ++mm) {
#pragma unroll
    for (int nn = 0; nn < 4; ++nn) {
      const int col = col0 + nn * 16;
      const float bv = bias[col];
      const int which = col >> 10;          // 0=q 1=k 2=v
      const int rem   = col & 1023;
      const int hh    = rem >> 6;
      const int dh    = rem & 63;
      // q scaled by DH^-0.5 * log2(e): softmax runs in exp2 domain
      const float scale = (which == 0) ? 0.18033688f : 1.0f;
#pragma unroll
      for (int rr = 0; rr < 4; ++rr) {
        const int row = row0 + mm * 16 + rr;  // t = s*B + b
        const int ss2 = row >> 2, bb2 = row & 3;
        const float v = (acc[mm][nn][rr] + bv) * scale;
        qkvb[(size_t)which * 4194304 +
             ((size_t)(bb2 * 16 + hh)) * 65536 + (size_t)ss2 * 64 + dh] = f2bf(v);
      }
    }
  }
}

// ---------------- out-proj GEMM: 128x128, row-major LDS, 2-phase -----------
// (round-4 proven version) C(fp32) = acc + bias + resid.
__global__ __launch_bounds__(256, 2) void gemm_bt(
    const bf16* __restrict__ A, const bf16* __restrict__ B,
    const float* __restrict__ bias, const float* __restrict__ resid,
    float* __restrict__ C, int N, int K) {
  __shared__ bf16 sA[2][128 * 32];
  __shared__ bf16 sB[2][128 * 32];
  const int tid  = threadIdx.x;
  const int brow = blockIdx.y * 128;
  const int bcol = blockIdx.x * 128;
  const int wid  = tid >> 6;
  const int lane = tid & 63;
  const int wr   = wid >> 1;
  const int wc   = wid & 1;
  const int fr   = lane & 15;
  const int fk   = lane >> 4;

  fx4 acc[4][4];
#pragma unroll
  for (int i = 0; i < 4; ++i)
#pragma unroll
    for (int j = 0; j < 4; ++j) acc[i][j] = 0.f;

  const int arow = tid >> 2;
  const int acol = (tid & 3) * 8;

  auto stage = [&](int buf, int kt) {
#pragma unroll
    for (int is = 0; is < 2; ++is) {
      const int row = is * 64 + arow;
      const int off = row * 64 + acol * 2;
      g2l16(A + (size_t)(brow + row) * K + kt + acol, (char*)sA[buf] + off);
      g2l16(B + (size_t)(bcol + row) * K + kt + acol, (char*)sB[buf] + off);
    }
  };

  stage(0, 0);
  asm volatile("s_waitcnt vmcnt(0)" ::: "memory");
  __builtin_amdgcn_s_barrier();
  asm volatile("" ::: "memory");

  const int nk = K >> 5;
  int cur = 0;
#pragma unroll 1
  for (int ki = 0; ki < nk; ++ki) {
    if (ki + 1 < nk) stage(cur ^ 1, (ki + 1) * 32);
    asm volatile("" ::: "memory");

    bx8 af[4], bfr[4];
#pragma unroll
    for (int mm = 0; mm < 4; ++mm)
      af[mm] = *(const bx8*)(sA[cur] + (wr * 64 + mm * 16 + fr) * 32 + fk * 8);
#pragma unroll
    for (int nn = 0; nn < 4; ++nn)
      bfr[nn] = *(const bx8*)(sB[cur] + (wc * 64 + nn * 16 + fr) * 32 + fk * 8);
#pragma unroll
    for (int mm = 0; mm < 4; ++mm)
#pragma unroll
      for (int nn = 0; nn < 4; ++nn)
        acc[mm][nn] = __builtin_amdgcn_mfma_f32_16x16x32_bf16(
            af[mm], bfr[nn], acc[mm][nn], 0, 0, 0);

    if (ki + 1 < nk) {
      asm volatile("s_waitcnt vmcnt(0)" ::: "memory");
      __builtin_amdgcn_s_barrier();
      asm volatile("" ::: "memory");
    }
    cur ^= 1;
  }

  const int row0 = brow + wr * 64 + fk * 4;
  const int col0 = bcol + wc * 64 + fr;
#pragma unroll
  for (int mm = 0; mm < 4; ++mm) {
#pragma unroll
    for (int nn = 0; nn < 4; ++nn) {
      const int col = col0 + nn * 16;
      const float bv = bias[col];
#pragma unroll
      for (int rr = 0; rr < 4; ++rr) {
        const int row = row0 + mm * 16 + rr;
        C[(size_t)row * N + col] = acc[mm][nn][rr] + bv + resid[(size_t)row * N + col];
      }
    }
  }
}

// ---------------- V [bh][s][64] -> V^T [bh][dh][1024] ----------------
__global__ __launch_bounds__(256) void transpose_v(
    const ushort* __restrict__ v, ushort* __restrict__ vt) {
  __shared__ ushort tile[64][65];
  const int g  = blockIdx.x;
  const int bh = g >> 4, st = g & 15;
  const int s0 = st * 64;
  const int tid = threadIdx.x;
  const int r  = tid >> 2;          // 0..63
  const int c0 = (tid & 3) * 16;    // 0,16,32,48
  const ushort* src = v + (size_t)bh * 65536 + (size_t)(s0 + r) * 64 + c0;
#pragma unroll
  for (int i = 0; i < 2; ++i) {
    const bx8 d = *(const bx8*)(src + i * 8);
#pragma unroll
    for (int j = 0; j < 8; ++j) tile[r][c0 + i * 8 + j] = (ushort)d[j];
  }
  __syncthreads();
  ushort* dst = vt + (size_t)bh * 65536 + (size_t)r * 1024 + s0 + c0;
  bx8 w0, w1;
#pragma unroll
  for (int j = 0; j < 8; ++j) {
    w0[j] = (short)tile[c0 + j][r];
    w1[j] = (short)tile[c0 + 8 + j][r];
  }
  *(bx8*)dst = w0;
  *(bx8*)(dst + 8) = w1;
}

// ---------------- MFMA flash attention ----------------
// One q-tile (64 rows) per block, grid 1024 = 4 blocks/CU. Big tiles first.
// Swapped S^T = mfma(K,Q); exp2-domain softmax; truncating bf16 P-pack;
// 2-phase pipelined LDS, defer-max, setprio.
__global__ __launch_bounds__(256, 4) void attn_mfma(
    const ushort* __restrict__ qb, const ushort* __restrict__ kb,
    const ushort* __restrict__ vtb, ushort* __restrict__ ob) {
  __shared__ __align__(16) char sK[2][8192];
  __shared__ __align__(16) char sVT[2][8192];
  __shared__ __align__(16) char sP[8192];
  const int tid  = threadIdx.x;
  const int wid  = tid >> 6;
  const int lane = tid & 63;
  const int g    = blockIdx.x;
  const int qt   = 15 - (g >> 6);   // descending work
  const int bh   = g & 63;
  const int b    = bh >> 4, h = bh & 15;
  const int fr   = lane & 15;
  const int fk   = lane >> 4;
  const size_t bhoff = (size_t)bh * 65536;
  char* const sPw = sP + wid * 2048;
  const int swp = (fr & 7) << 4;

  auto stage = [&](int buf, int k0) {
#pragma unroll
    for (int is = 0; is < 2; ++is) {
      const int L    = is * 4096 + tid * 16;
      const int row  = L >> 7;
      const int colb = (L & 127) ^ ((row & 7) << 4);
      g2l16(kb  + bhoff + (size_t)(k0 + row) * 64 + (colb >> 1), sK[buf]  + L);
      g2l16(vtb + bhoff + (size_t)row * 1024 + k0 + (colb >> 1), sVT[buf] + L);
    }
  };

  const int q0w = qt * 64 + wid * 16;
  const ushort* qp = qb + bhoff + (size_t)(q0w + fr) * 64;
  const bx8 qf0 = *(const bx8*)(qp + fk * 8);
  const bx8 qf1 = *(const bx8*)(qp + 32 + fk * 8);
  asm volatile("s_waitcnt vmcnt(0)" ::: "memory");

  fx4 o4[4];
  float m = -3e38f, l = 0.f;
#pragma unroll
  for (int dt = 0; dt < 4; ++dt) o4[dt] = 0.f;

  stage(0, 0);
  int cur = 0;

#pragma unroll 1
  for (int kbk = 0; kbk <= qt; ++kbk) {
    if (kbk < qt) {
      stage(cur ^ 1, (kbk + 1) * 64);
      asm volatile("s_waitcnt vmcnt(4)" ::: "memory");
    } else {
      asm volatile("s_waitcnt vmcnt(0)" ::: "memory");
    }
    __builtin_amdgcn_s_barrier();
    asm volatile("" ::: "memory");
    const char* sKc  = sK[cur];
    const char* sVTc = sVT[cur];

    fx4 s4[4];
    __builtin_amdgcn_s_setprio(1);
#pragma unroll
    for (int kt = 0; kt < 4; ++kt) {
      const int krow = kt * 16 + fr;
      const int sw   = (krow & 7) << 4;
      const bx8 kf0 = *(const bx8*)(sKc + krow * 128 + ((fk * 16) ^ sw));
      const bx8 kf1 = *(const bx8*)(sKc + krow * 128 + ((64 + fk * 16) ^ sw));
      fx4 z = {0.f, 0.f, 0.f, 0.f};
      z = __builtin_amdgcn_mfma_f32_16x16x32_bf16(kf0, qf0, z, 0, 0, 0);
      s4[kt] = __builtin_amdgcn_mfma_f32_16x16x32_bf16(kf1, qf1, z, 0, 0, 0);
    }
    __builtin_amdgcn_s_setprio(0);

    if (kbk == qt) {
      const int qloc = wid * 16 + fr;
#pragma unroll
      for (int kt = 0; kt < 4; ++kt) {
        const int keyb = kt * 16 + fk * 4;
#pragma unroll
        for (int rr = 0; rr < 4; ++rr)
          if (keyb + rr > qloc) s4[kt][rr] = -3e38f;
      }
    }

    float pm = s4[0][0];
#pragma unroll
    for (int kt = 0; kt < 4; ++kt)
#pragma unroll
      for (int rr = 0; rr < 4; ++rr) pm = fmaxf(pm, s4[kt][rr]);
    pm = fmaxf(pm, __shfl_xor(pm, 16));
    pm = fmaxf(pm, __shfl_xor(pm, 32));

    if (__any(pm > m + 11.5f)) {
      const float mn = fmaxf(m, pm);
      const float f  = exp2f(m - mn);
      m = mn;
      l *= f;
      float fq[4];
#pragma unroll
      for (int rr = 0; rr < 4; ++rr) fq[rr] = __shfl(f, fk * 4 + rr);
#pragma unroll
      for (int dt = 0; dt < 4; ++dt)
#pragma unroll
        for (int rr = 0; rr < 4; ++rr) o4[dt][rr] *= fq[rr];
    }

#pragma unroll
    for (int kt = 0; kt < 4; ++kt) {
      union { float f; unsigned u; } a0, a1, a2, a3;
      a0.f = exp2f(s4[kt][0] - m);
      a1.f = exp2f(s4[kt][1] - m);
      a2.f = exp2f(s4[kt][2] - m);
      a3.f = exp2f(s4[kt][3] - m);
      l += (a0.f + a1.f) + (a2.f + a3.f);
      uint2 pk;
      pk.x = (a0.u >> 16) | (a1.u & 0xFFFF0000u);
      pk.y = (a2.u >> 16) | (a3.u & 0xFFFF0000u);
      *(uint2*)(sPw + ((fr * 128 + kt * 32 + fk * 8) ^ swp)) = pk;
    }

    __builtin_amdgcn_s_setprio(1);
#pragma unroll
    for (int c = 0; c < 2; ++c) {
      const bx8 pa = *(const bx8*)(sPw + ((fr * 128 + c * 64 + fk * 16) ^ swp));
#pragma unroll
      for (int dt = 0; dt < 4; ++dt) {
        const int vrow = dt * 16 + fr;
        const bx8 vf = *(const bx8*)(sVTc + vrow * 128 +
                                     ((c * 64 + fk * 16) ^ ((vrow & 7) << 4)));
        o4[dt] = __builtin_amdgcn_mfma_f32_16x16x32_bf16(pa, vf, o4[dt], 0, 0, 0);
      }
    }
    __builtin_amdgcn_s_setprio(0);

    asm volatile("" ::: "memory");
    __builtin_amdgcn_s_barrier();
    asm volatile("" ::: "memory");
    cur ^= 1;
  }

  l += __shfl_xor(l, 16);
  l += __shfl_xor(l, 32);
  const float linv = 1.f / l;
  float lq[4];
#pragma unroll
  for (int rr = 0; rr < 4; ++rr) lq[rr] = __shfl(linv, fk * 4 + rr);

#pragma unroll
  for (int dt = 0; dt < 4; ++dt) {
#pragma unroll
    for (int rr = 0; rr < 4; ++rr) {
      const int qq = q0w + fk * 4 + rr;
      ob[((size_t)qq * 4 + b) * 1024 + h * 64 + dt * 16 + fr] =
          f2bf(o4[dt][rr] * lq[rr]);
    }
  }
}

// ---------------- LN2 + router + gate + final multiply ----------------
__global__ __launch_bounds__(256) void final_kernel(
    const float* __restrict__ xn, const float* __restrict__ w,
    const float* __restrict__ bb, const float* __restrict__ gw,
    float* __restrict__ out, float* __restrict__ rlog) {
  const int t = blockIdx.x, tid = threadIdx.x;
  const fx4 v = ((const fx4*)(xn + (size_t)t * D_DIM))[tid];
  float s  = v[0] + v[1] + v[2] + v[3];
  float ss = v[0]*v[0] + v[1]*v[1] + v[2]*v[2] + v[3]*v[3];
#pragma unroll
  for (int off = 32; off >= 1; off >>= 1) {
    s  += __shfl_xor(s, off);
    ss += __shfl_xor(ss, off);
  }
  __shared__ float red[8];
  __shared__ float red2[12];
  const int wid = tid >> 6, lane = tid & 63;
  if (lane == 0) { red[wid] = s; red[4 + wid] = ss; }
  __syncthreads();
  s  = red[0] + red[1] + red[2] + red[3];
  ss = red[4] + red[5] + red[6] + red[7];
  const float mu = s * (1.f / D_DIM);
  const float rstd = rsqrtf(ss * (1.f / D_DIM) - mu * mu + 1e-5f);
  const fx4 wv = ((const fx4*)w)[tid];
  const fx4 bv = ((const fx4*)bb)[tid];
  fx4 hv;
#pragma unroll
  for (int cc = 0; cc < 4; ++cc) hv[cc] = (v[cc] - mu) * rstd * wv[cc] + bv[cc];

  const fx4 w0 = ((const fx4*)(gw           ))[tid];
  const fx4 w1 = ((const fx4*)(gw +     D_DIM))[tid];
  const fx4 w2 = ((const fx4*)(gw + 2 * D_DIM))[tid];
  float g0 = hv[0]*w0[0] + hv[1]*w0[1] + hv[2]*w0[2] + hv[3]*w0[3];
  float g1 = hv[0]*w1[0] + hv[1]*w1[1] + hv[2]*w1[2] + hv[3]*w1[3];
  float g2 = hv[0]*w2[0] + hv[1]*w2[1] + hv[2]*w2[2] + hv[3]*w2[3];
#pragma unroll
  for (int off = 32; off >= 1; off >>= 1) {
    g0 += __shfl_xor(g0, off);
    g1 += __shfl_xor(g1, off);
    g2 += __shfl_xor(g2, off);
  }
  if (lane == 0) { red2[wid] = g0; red2[4 + wid] = g1; red2[8 + wid] = g2; }
  __syncthreads();
  g0 = red2[0] + red2[1] + red2[2]  + red2[3];
  g1 = red2[4] + red2[5] + red2[6]  + red2[7];
  g2 = red2[8] + red2[9] + red2[10] + red2[11];

  const float lmax = fmaxf(g0, fmaxf(g1, g2));
  const float lmin = fminf(g0, fminf(g1, g2));
  const float lmid = (g0 + g1 + g2) - lmax - lmin;
  const float gate = 1.f / (1.f + __expf(lmid - lmax));

  ((fx4*)(out + (size_t)t * D_DIM))[tid] = v * gate;
  if (tid == 0) {
    rlog[(size_t)t * 3 + 0] = g0;
    rlog[(size_t)t * 3 + 1] = g1;
    rlog[(size_t)t * 3 + 2] = g2;
  }
}

extern "C" void kernel_launch(void* const* d_in, const int* in_sizes, int n_in,
                              void* d_out, int out_size, void* d_ws, size_t ws_size,
                              hipStream_t stream) {
  (void)in_sizes; (void)n_in; (void)out_size; (void)ws_size;
  const float* x    = (const float*)d_in[0];
  const float* ln1w = (const float*)d_in[1];
  const float* ln1b = (const float*)d_in[2];
  const float* ln2w = (const float*)d_in[3];
  const float* ln2b = (const float*)d_in[4];
  const float* win  = (const float*)d_in[5];
  const float* bin  = (const float*)d_in[6];
  const float* wout = (const float*)d_in[7];
  const float* bout = (const float*)d_in[8];
  const float* gw   = (const float*)d_in[9];
  // fc_w / fc_b / proj_w / proj_b (d_in[10..13]) are dead code in the reference.

  char* ws = (char*)d_ws;
  bf16*   w_in_b  = (bf16*)(ws);               // 6 MiB
  bf16*   w_out_b = (bf16*)(ws + 6291456);     // 2 MiB
  bf16*   h_b     = (bf16*)(ws + 8388608);     // 8 MiB (LN1 out; o_b aliases)
  ushort* o_b     = (ushort*)h_b;              // alias: h dead after GEMM1
  ushort* qkvb    = (ushort*)(ws + 16777216);  // 24 MiB: q/k/v bf16 [bh][s][64]
  ushort* q_b     = qkvb;
  ushort* k_b     = qkvb + 4194304;
  ushort* v_b     = qkvb + 8388608;
  float*  xnew    = (float*)(ws + 41943040);   // 16 MiB
  ushort* vt_b    = (ushort*)(ws + 58720256);  // 8 MiB: V^T [bh][dh][s]
  // total ws use: 64 MiB

  float* out  = (float*)d_out;
  float* rlog = out + (size_t)T_DIM * D_DIM;

  cast2_f32_bf16<<<4096, 256, 0, stream>>>(win, w_in_b, 786432,
                                           wout, w_out_b, 262144);
  ln_bf16_kernel<<<T_DIM, 256, 0, stream>>>(x, ln1w, ln1b, h_b);
  gemm_qkv8<<<192, 512, 0, stream>>>(h_b, w_in_b, bin, qkvb, D_DIM);
  transpose_v<<<1024, 256, 0, stream>>>(v_b, vt_b);
  attn_mfma<<<1024, 256, 0, stream>>>(q_b, k_b, vt_b, o_b);
  gemm_bt<<<dim3(D_DIM / 128, T_DIM / 128), 256, 0, stream>>>(
      (const bf16*)o_b, w_out_b, bout, x, xnew, D_DIM, D_DIM);
  final_kernel<<<T_DIM, 256, 0, stream>>>(xnew, ln2w, ln2b, gw, out, rlog);
}

// Round 8
// 115.485 us; speedup vs baseline: 1.2817x; 1.0685x over previous
//
#include <hip/hip_runtime.h>
#include <hip/hip_bf16.h>

#define S_DIM 1024
#define B_DIM 4
#define D_DIM 1024
#define H_DIM 16
#define DH    64
#define T_DIM (S_DIM * B_DIM)   // 4096
#define QKV_N (3 * D_DIM)       // 3072

using bf16 = __hip_bfloat16;
typedef __attribute__((ext_vector_type(4))) float fx4;
typedef __attribute__((ext_vector_type(8))) short bx8;

__device__ __forceinline__ unsigned short f2bf(float f) {
  union { float f; unsigned int u; } cv; cv.f = f;
  unsigned int u = cv.u;
  unsigned int r = (u + 0x7FFFu + ((u >> 16) & 1u)) >> 16;  // RNE
  return (unsigned short)r;
}

__device__ __forceinline__ void g2l16(const void* g, void* l) {
  __builtin_amdgcn_global_load_lds(
      (const __attribute__((address_space(1))) unsigned int*)g,
      (__attribute__((address_space(3))) unsigned int*)l, 16, 0, 0);
}

// ---------------- prep: LN1->bf16 (blocks 0..4095) + weight casts ----------
__global__ __launch_bounds__(256) void prep_kernel(
    const float* __restrict__ x, const float* __restrict__ w,
    const float* __restrict__ bb, bf16* __restrict__ out,
    const float* __restrict__ win, bf16* __restrict__ winb,
    const float* __restrict__ wout, bf16* __restrict__ woutb) {
  const int blk = blockIdx.x, tid = threadIdx.x;
  if (blk >= 4096) {  // weight cast: 1048576 fx4 chunks total
    const int i = (blk - 4096) * 256 + tid;
    const float* src; bf16* dst; int j;
    if (i < 786432) { src = win; dst = winb; j = i; }
    else { src = wout; dst = woutb; j = i - 786432; }
    const fx4 v = ((const fx4*)src)[j];
    ushort4 u;
    u.x = f2bf(v[0]); u.y = f2bf(v[1]); u.z = f2bf(v[2]); u.w = f2bf(v[3]);
    ((ushort4*)dst)[j] = u;
    return;
  }
  const int t = blk;
  const fx4 v = ((const fx4*)(x + (size_t)t * D_DIM))[tid];
  float s  = v[0] + v[1] + v[2] + v[3];
  float ss = v[0]*v[0] + v[1]*v[1] + v[2]*v[2] + v[3]*v[3];
#pragma unroll
  for (int off = 32; off >= 1; off >>= 1) {
    s  += __shfl_xor(s, off);
    ss += __shfl_xor(ss, off);
  }
  __shared__ float red[8];
  const int wid = tid >> 6, lane = tid & 63;
  if (lane == 0) { red[wid] = s; red[4 + wid] = ss; }
  __syncthreads();
  s  = red[0] + red[1] + red[2] + red[3];
  ss = red[4] + red[5] + red[6] + red[7];
  const float mu = s * (1.f / D_DIM);
  const float rstd = rsqrtf(ss * (1.f / D_DIM) - mu * mu + 1e-5f);
  const fx4 wv = ((const fx4*)w)[tid];
  const fx4 bv = ((const fx4*)bb)[tid];
  ushort4 u;
  u.x = f2bf((v[0] - mu) * rstd * wv[0] + bv[0]);
  u.y = f2bf((v[1] - mu) * rstd * wv[1] + bv[1]);
  u.z = f2bf((v[2] - mu) * rstd * wv[2] + bv[2]);
  u.w = f2bf((v[3] - mu) * rstd * wv[3] + bv[3]);
  ((ushort4*)(out + (size_t)t * D_DIM))[tid] = u;
}

// ---------------- qkv GEMM (round-4 proven): 128x128, 2-phase dbuf ---------
// qkv split-write bf16 [bh][s][64]; q pre-scaled by 0.125*log2(e).
__global__ __launch_bounds__(256, 2) void gemm_qkv(
    const bf16* __restrict__ A, const bf16* __restrict__ B,
    const float* __restrict__ bias, ushort* __restrict__ qkvb, int K) {
  __shared__ bf16 sA[2][128 * 32];
  __shared__ bf16 sB[2][128 * 32];
  const int tid  = threadIdx.x;
  const int brow = blockIdx.y * 128;
  const int bcol = blockIdx.x * 128;
  const int wid  = tid >> 6;
  const int lane = tid & 63;
  const int wr   = wid >> 1;
  const int wc   = wid & 1;
  const int fr   = lane & 15;
  const int fk   = lane >> 4;

  fx4 acc[4][4];
#pragma unroll
  for (int i = 0; i < 4; ++i)
#pragma unroll
    for (int j = 0; j < 4; ++j) acc[i][j] = 0.f;

  const int arow = tid >> 2;
  const int acol = (tid & 3) * 8;

  auto stage = [&](int buf, int kt) {
#pragma unroll
    for (int is = 0; is < 2; ++is) {
      const int row = is * 64 + arow;
      const int off = row * 64 + acol * 2;
      g2l16(A + (size_t)(brow + row) * K + kt + acol, (char*)sA[buf] + off);
      g2l16(B + (size_t)(bcol + row) * K + kt + acol, (char*)sB[buf] + off);
    }
  };

  stage(0, 0);
  asm volatile("s_waitcnt vmcnt(0)" ::: "memory");
  __builtin_amdgcn_s_barrier();
  asm volatile("" ::: "memory");

  const int nk = K >> 5;
  int cur = 0;
#pragma unroll 1
  for (int ki = 0; ki < nk; ++ki) {
    if (ki + 1 < nk) stage(cur ^ 1, (ki + 1) * 32);
    asm volatile("" ::: "memory");

    bx8 af[4], bfr[4];
#pragma unroll
    for (int mm = 0; mm < 4; ++mm)
      af[mm] = *(const bx8*)(sA[cur] + (wr * 64 + mm * 16 + fr) * 32 + fk * 8);
#pragma unroll
    for (int nn = 0; nn < 4; ++nn)
      bfr[nn] = *(const bx8*)(sB[cur] + (wc * 64 + nn * 16 + fr) * 32 + fk * 8);
#pragma unroll
    for (int mm = 0; mm < 4; ++mm)
#pragma unroll
      for (int nn = 0; nn < 4; ++nn)
        acc[mm][nn] = __builtin_amdgcn_mfma_f32_16x16x32_bf16(
            af[mm], bfr[nn], acc[mm][nn], 0, 0, 0);

    if (ki + 1 < nk) {
      asm volatile("s_waitcnt vmcnt(0)" ::: "memory");
      __builtin_amdgcn_s_barrier();
      asm volatile("" ::: "memory");
    }
    cur ^= 1;
  }

  // C/D layout: col = lane&15, row = (lane>>4)*4 + reg
  const int row0 = brow + wr * 64 + fk * 4;
  const int col0 = bcol + wc * 64 + fr;
#pragma unroll
  for (int mm = 0; mm < 4; ++mm) {
#pragma unroll
    for (int nn = 0; nn < 4; ++nn) {
      const int col = col0 + nn * 16;
      const float bv = bias[col];
      const int which = col >> 10;          // 0=q 1=k 2=v
      const int rem   = col & 1023;
      const int hh    = rem >> 6;
      const int dh    = rem & 63;
      // q scaled by DH^-0.5 * log2(e): softmax runs in exp2 domain
      const float scale = (which == 0) ? 0.18033688f : 1.0f;
#pragma unroll
      for (int rr = 0; rr < 4; ++rr) {
        const int row = row0 + mm * 16 + rr;  // t = s*B + b
        const int ss2 = row >> 2, bb2 = row & 3;
        const float v = (acc[mm][nn][rr] + bv) * scale;
        qkvb[(size_t)which * 4194304 +
             ((size_t)(bb2 * 16 + hh)) * 65536 + (size_t)ss2 * 64 + dh] = f2bf(v);
      }
    }
  }
}

// ---------------- V [bh][s][64] -> V^T [bh][dh][1024] ----------------
__global__ __launch_bounds__(256) void transpose_v(
    const ushort* __restrict__ v, ushort* __restrict__ vt) {
  __shared__ ushort tile[64][65];
  const int g  = blockIdx.x;
  const int bh = g >> 4, st = g & 15;
  const int s0 = st * 64;
  const int tid = threadIdx.x;
  const int r  = tid >> 2;          // 0..63
  const int c0 = (tid & 3) * 16;    // 0,16,32,48
  const ushort* src = v + (size_t)bh * 65536 + (size_t)(s0 + r) * 64 + c0;
#pragma unroll
  for (int i = 0; i < 2; ++i) {
    const bx8 d = *(const bx8*)(src + i * 8);
#pragma unroll
    for (int j = 0; j < 8; ++j) tile[r][c0 + i * 8 + j] = (ushort)d[j];
  }
  __syncthreads();
  ushort* dst = vt + (size_t)bh * 65536 + (size_t)r * 1024 + s0 + c0;
  bx8 w0, w1;
#pragma unroll
  for (int j = 0; j < 8; ++j) {
    w0[j] = (short)tile[c0 + j][r];
    w1[j] = (short)tile[c0 + 8 + j][r];
  }
  *(bx8*)dst = w0;
  *(bx8*)(dst + 8) = w1;
}

// ---------------- MFMA flash attention: 2 q-tiles share K/V staging --------
// 512-thread block: waves 0-3 own q-tile pr, waves 4-7 own 15-pr (uniform
// 17 compute-iters/block). One K/VT stage per iter serves both tiles ->
// staging traffic halved. Grid 512 = whole grid resident, 2 blocks/CU;
// bid&7 = bh&7 keeps each bh's K/V on one XCD L2 (8 bh x 256KB = 2MB).
// Swapped S^T = mfma(K,Q); exp2-domain softmax; truncating bf16 P-pack;
// 2-phase counted-vmcnt pipeline; defer-max; setprio.
__global__ __launch_bounds__(512, 4) void attn_mfma(
    const ushort* __restrict__ qb, const ushort* __restrict__ kb,
    const ushort* __restrict__ vtb, ushort* __restrict__ ob) {
  __shared__ __align__(16) char sK[2][8192];
  __shared__ __align__(16) char sVT[2][8192];
  __shared__ __align__(16) char sP[16384];
  const int tid  = threadIdx.x;
  const int wid  = tid >> 6;        // 0..7
  const int lane = tid & 63;
  const int bid  = blockIdx.x;
  const int xcd  = bid & 7;
  const int r2   = bid >> 3;        // 0..63
  const int pr   = r2 & 7;
  const int bh   = (r2 >> 3) * 8 + xcd;
  const int b    = bh >> 4, h = bh & 15;
  const int fr   = lane & 15;
  const int fk   = lane >> 4;
  const size_t bhoff = (size_t)bh * 65536;
  char* const sPw = sP + wid * 2048;
  const int swp = (fr & 7) << 4;
  const int qt_max  = 15 - pr;
  const int qt_mine = (wid < 4) ? pr : qt_max;
  const int wid4 = wid & 3;

  // stage: 512 threads cover the full 8KB K-tile and 8KB VT-tile (1 load ea.)
  auto stage = [&](int buf, int k0) {
    const int L    = tid * 16;
    const int row  = L >> 7;
    const int colb = (L & 127) ^ ((row & 7) << 4);
    g2l16(kb  + bhoff + (size_t)(k0 + row) * 64 + (colb >> 1), sK[buf]  + L);
    g2l16(vtb + bhoff + (size_t)row * 1024 + k0 + (colb >> 1), sVT[buf] + L);
  };

  const int q0w = qt_mine * 64 + wid4 * 16;
  const ushort* qp = qb + bhoff + (size_t)(q0w + fr) * 64;
  const bx8 qf0 = *(const bx8*)(qp + fk * 8);
  const bx8 qf1 = *(const bx8*)(qp + 32 + fk * 8);
  asm volatile("s_waitcnt vmcnt(0)" ::: "memory");  // exact vmcnt counting

  fx4 o4[4];
  float m = -3e38f, l = 0.f;
#pragma unroll
  for (int dt = 0; dt < 4; ++dt) o4[dt] = 0.f;

  stage(0, 0);   // 2 loads/thread outstanding

#pragma unroll 1
  for (int kbk = 0; kbk <= qt_max; ++kbk) {
    const int cur = kbk & 1;
    if (kbk < qt_max) {
      stage(cur ^ 1, (kbk + 1) * 64);                   // +2 -> 4 outstanding
      asm volatile("s_waitcnt vmcnt(2)" ::: "memory");  // cur's 2 landed
    } else {
      asm volatile("s_waitcnt vmcnt(0)" ::: "memory");
    }
    __builtin_amdgcn_s_barrier();
    asm volatile("" ::: "memory");

    if (kbk <= qt_mine) {   // wave-uniform guard; no barriers inside
      const char* sKc  = sK[cur];
      const char* sVTc = sVT[cur];

      // --- S^T = mfma(K, Q): s4[kt][rr] = S[key=kt*16+fk*4+rr][q=fr] ---
      fx4 s4[4];
      __builtin_amdgcn_s_setprio(1);
#pragma unroll
      for (int kt = 0; kt < 4; ++kt) {
        const int krow = kt * 16 + fr;
        const int sw   = (krow & 7) << 4;
        const bx8 kf0 = *(const bx8*)(sKc + krow * 128 + ((fk * 16) ^ sw));
        const bx8 kf1 = *(const bx8*)(sKc + krow * 128 + ((64 + fk * 16) ^ sw));
        fx4 z = {0.f, 0.f, 0.f, 0.f};
        z = __builtin_amdgcn_mfma_f32_16x16x32_bf16(kf0, qf0, z, 0, 0, 0);
        s4[kt] = __builtin_amdgcn_mfma_f32_16x16x32_bf16(kf1, qf1, z, 0, 0, 0);
      }
      __builtin_amdgcn_s_setprio(0);

      if (kbk == qt_mine) {  // diagonal: wave-relative causal mask
        const int qloc = wid4 * 16 + fr;
#pragma unroll
        for (int kt = 0; kt < 4; ++kt) {
          const int keyb = kt * 16 + fk * 4;
#pragma unroll
          for (int rr = 0; rr < 4; ++rr)
            if (keyb + rr > qloc) s4[kt][rr] = -3e38f;
        }
      }

      // --- online softmax in exp2 domain: lane owns q=fr ---
      float pm = s4[0][0];
#pragma unroll
      for (int kt = 0; kt < 4; ++kt)
#pragma unroll
        for (int rr = 0; rr < 4; ++rr) pm = fmaxf(pm, s4[kt][rr]);
      pm = fmaxf(pm, __shfl_xor(pm, 16));
      pm = fmaxf(pm, __shfl_xor(pm, 32));

      if (__any(pm > m + 11.5f)) {   // defer-max (T13), 8 nats in bits
        const float mn = fmaxf(m, pm);
        const float f  = exp2f(m - mn);
        m = mn;
        l *= f;
        float fq[4];
#pragma unroll
        for (int rr = 0; rr < 4; ++rr) fq[rr] = __shfl(f, fk * 4 + rr);
#pragma unroll
        for (int dt = 0; dt < 4; ++dt)
#pragma unroll
          for (int rr = 0; rr < 4; ++rr) o4[dt][rr] *= fq[rr];
      }

      // --- P = exp2(S-m), truncating bf16 pack, b64 LDS writes ---
#pragma unroll
      for (int kt = 0; kt < 4; ++kt) {
        union { float f; unsigned u; } a0, a1, a2, a3;
        a0.f = exp2f(s4[kt][0] - m);
        a1.f = exp2f(s4[kt][1] - m);
        a2.f = exp2f(s4[kt][2] - m);
        a3.f = exp2f(s4[kt][3] - m);
        l += (a0.f + a1.f) + (a2.f + a3.f);
        uint2 pk;
        pk.x = (a0.u >> 16) | (a1.u & 0xFFFF0000u);
        pk.y = (a2.u >> 16) | (a3.u & 0xFFFF0000u);
        *(uint2*)(sPw + ((fr * 128 + kt * 32 + fk * 8) ^ swp)) = pk;
      }

      // --- O += P V ---
      __builtin_amdgcn_s_setprio(1);
#pragma unroll
      for (int c = 0; c < 2; ++c) {
        const bx8 pa = *(const bx8*)(sPw + ((fr * 128 + c * 64 + fk * 16) ^ swp));
#pragma unroll
        for (int dt = 0; dt < 4; ++dt) {
          const int vrow = dt * 16 + fr;
          const bx8 vf = *(const bx8*)(sVTc + vrow * 128 +
                                       ((c * 64 + fk * 16) ^ ((vrow & 7) << 4)));
          o4[dt] = __builtin_amdgcn_mfma_f32_16x16x32_bf16(pa, vf, o4[dt], 0, 0, 0);
        }
      }
      __builtin_amdgcn_s_setprio(0);
    }

    asm volatile("" ::: "memory");
    __builtin_amdgcn_s_barrier();   // readers done before next overwrite
    asm volatile("" ::: "memory");
  }

  // --- epilogue: total row sums, per-output-row norms, store ---
  l += __shfl_xor(l, 16);
  l += __shfl_xor(l, 32);
  const float linv = 1.f / l;
  float lq[4];
#pragma unroll
  for (int rr = 0; rr < 4; ++rr) lq[rr] = __shfl(linv, fk * 4 + rr);

#pragma unroll
  for (int dt = 0; dt < 4; ++dt) {
#pragma unroll
    for (int rr = 0; rr < 4; ++rr) {
      const int qq = q0w + fk * 4 + rr;
      ob[((size_t)qq * 4 + b) * 1024 + h * 64 + dt * 16 + fr] =
          f2bf(o4[dt][rr] * lq[rr]);
    }
  }
}

// ---------------- out-proj GEMM: 128x64 tiles (grid 512 = 2/CU) ------------
// C(fp32)[4096,1024] = A[4096,1024] @ B[1024,1024]^T + bias + resid.
__global__ __launch_bounds__(256, 2) void gemm_out(
    const bf16* __restrict__ A, const bf16* __restrict__ B,
    const float* __restrict__ bias, const float* __restrict__ resid,
    float* __restrict__ C) {
  __shared__ bf16 sA[2][128 * 32];
  __shared__ bf16 sB[2][64 * 32];
  const int tid  = threadIdx.x;
  const int brow = blockIdx.y * 128;
  const int bcol = blockIdx.x * 64;
  const int wid  = tid >> 6;
  const int lane = tid & 63;
  const int wr   = wid >> 1;      // 0..1: 64-row stripe
  const int wc   = wid & 1;       // 0..1: 32-col stripe
  const int fr   = lane & 15;
  const int fk   = lane >> 4;

  fx4 acc[4][2];
#pragma unroll
  for (int i = 0; i < 4; ++i)
#pragma unroll
    for (int j = 0; j < 2; ++j) acc[i][j] = 0.f;

  const int arow = tid >> 2;
  const int acol = (tid & 3) * 8;

  auto stage = [&](int buf, int kt) {
#pragma unroll
    for (int is = 0; is < 2; ++is) {
      const int row = is * 64 + arow;
      g2l16(A + (size_t)(brow + row) * 1024 + kt + acol,
            (char*)sA[buf] + row * 64 + acol * 2);
    }
    g2l16(B + (size_t)(bcol + arow) * 1024 + kt + acol,
          (char*)sB[buf] + arow * 64 + acol * 2);
  };

  stage(0, 0);
  asm volatile("s_waitcnt vmcnt(0)" ::: "memory");
  __builtin_amdgcn_s_barrier();
  asm volatile("" ::: "memory");

  int cur = 0;
#pragma unroll 1
  for (int ki = 0; ki < 32; ++ki) {
    if (ki + 1 < 32) stage(cur ^ 1, (ki + 1) * 32);
    asm volatile("" ::: "memory");

    bx8 af[4], bfr[2];
#pragma unroll
    for (int mm = 0; mm < 4; ++mm)
      af[mm] = *(const bx8*)(sA[cur] + (wr * 64 + mm * 16 + fr) * 32 + fk * 8);
#pragma unroll
    for (int nn = 0; nn < 2; ++nn)
      bfr[nn] = *(const bx8*)(sB[cur] + (wc * 32 + nn * 16 + fr) * 32 + fk * 8);
#pragma unroll
    for (int mm = 0; mm < 4; ++mm)
#pragma unroll
      for (int nn = 0; nn < 2; ++nn)
        acc[mm][nn] = __builtin_amdgcn_mfma_f32_16x16x32_bf16(
            af[mm], bfr[nn], acc[mm][nn], 0, 0, 0);

    if (ki + 1 < 32) {
      asm volatile("s_waitcnt vmcnt(0)" ::: "memory");
      __builtin_amdgcn_s_barrier();
      asm volatile("" ::: "memory");
    }
    cur ^= 1;
  }

  const int row0 = brow + wr * 64 + fk * 4;
  const int col0 = bcol + wc * 32 + fr;
#pragma unroll
  for (int mm = 0; mm < 4; ++mm) {
#pragma unroll
    for (int nn = 0; nn < 2; ++nn) {
      const int col = col0 + nn * 16;
      const float bv = bias[col];
#pragma unroll
      for (int rr = 0; rr < 4; ++rr) {
        const int row = row0 + mm * 16 + rr;
        C[(size_t)row * 1024 + col] =
            acc[mm][nn][rr] + bv + resid[(size_t)row * 1024 + col];
      }
    }
  }
}

// ---------------- LN2 + router + gate + final multiply ----------------
__global__ __launch_bounds__(256) void final_kernel(
    const float* __restrict__ xn, const float* __restrict__ w,
    const float* __restrict__ bb, const float* __restrict__ gw,
    float* __restrict__ out, float* __restrict__ rlog) {
  const int t = blockIdx.x, tid = threadIdx.x;
  const fx4 v = ((const fx4*)(xn + (size_t)t * D_DIM))[tid];
  float s  = v[0] + v[1] + v[2] + v[3];
  float ss = v[0]*v[0] + v[1]*v[1] + v[2]*v[2] + v[3]*v[3];
#pragma unroll
  for (int off = 32; off >= 1; off >>= 1) {
    s  += __shfl_xor(s, off);
    ss += __shfl_xor(ss, off);
  }
  __shared__ float red[8];
  __shared__ float red2[12];
  const int wid = tid >> 6, lane = tid & 63;
  if (lane == 0) { red[wid] = s; red[4 + wid] = ss; }
  __syncthreads();
  s  = red[0] + red[1] + red[2] + red[3];
  ss = red[4] + red[5] + red[6] + red[7];
  const float mu = s * (1.f / D_DIM);
  const float rstd = rsqrtf(ss * (1.f / D_DIM) - mu * mu + 1e-5f);
  const fx4 wv = ((const fx4*)w)[tid];
  const fx4 bv = ((const fx4*)bb)[tid];
  fx4 hv;
#pragma unroll
  for (int cc = 0; cc < 4; ++cc) hv[cc] = (v[cc] - mu) * rstd * wv[cc] + bv[cc];

  const fx4 w0 = ((const fx4*)(gw           ))[tid];
  const fx4 w1 = ((const fx4*)(gw +     D_DIM))[tid];
  const fx4 w2 = ((const fx4*)(gw + 2 * D_DIM))[tid];
  float g0 = hv[0]*w0[0] + hv[1]*w0[1] + hv[2]*w0[2] + hv[3]*w0[3];
  float g1 = hv[0]*w1[0] + hv[1]*w1[1] + hv[2]*w1[2] + hv[3]*w1[3];
  float g2 = hv[0]*w2[0] + hv[1]*w2[1] + hv[2]*w2[2] + hv[3]*w2[3];
#pragma unroll
  for (int off = 32; off >= 1; off >>= 1) {
    g0 += __shfl_xor(g0, off);
    g1 += __shfl_xor(g1, off);
    g2 += __shfl_xor(g2, off);
  }
  if (lane == 0) { red2[wid] = g0; red2[4 + wid] = g1; red2[8 + wid] = g2; }
  __syncthreads();
  g0 = red2[0] + red2[1] + red2[2]  + red2[3];
  g1 = red2[4] + red2[5] + red2[6]  + red2[7];
  g2 = red2[8] + red2[9] + red2[10] + red2[11];

  // gate = pmax/(pmax+p2nd) of softmax over 3 = 1/(1+exp(l_mid - l_max))
  const float lmax = fmaxf(g0, fmaxf(g1, g2));
  const float lmin = fminf(g0, fminf(g1, g2));
  const float lmid = (g0 + g1 + g2) - lmax - lmin;
  const float gate = 1.f / (1.f + __expf(lmid - lmax));

  ((fx4*)(out + (size_t)t * D_DIM))[tid] = v * gate;
  if (tid == 0) {
    rlog[(size_t)t * 3 + 0] = g0;
    rlog[(size_t)t * 3 + 1] = g1;
    rlog[(size_t)t * 3 + 2] = g2;
  }
}

extern "C" void kernel_launch(void* const* d_in, const int* in_sizes, int n_in,
                              void* d_out, int out_size, void* d_ws, size_t ws_size,
                              hipStream_t stream) {
  (void)in_sizes; (void)n_in; (void)out_size; (void)ws_size;
  const float* x    = (const float*)d_in[0];
  const float* ln1w = (const float*)d_in[1];
  const float* ln1b = (const float*)d_in[2];
  const float* ln2w = (const float*)d_in[3];
  const float* ln2b = (const float*)d_in[4];
  const float* win  = (const float*)d_in[5];
  const float* bin  = (const float*)d_in[6];
  const float* wout = (const float*)d_in[7];
  const float* bout = (const float*)d_in[8];
  const float* gw   = (const float*)d_in[9];
  // fc_w / fc_b / proj_w / proj_b (d_in[10..13]) are dead code in the reference.

  char* ws = (char*)d_ws;
  bf16*   w_in_b  = (bf16*)(ws);               // 6 MiB
  bf16*   w_out_b = (bf16*)(ws + 6291456);     // 2 MiB
  bf16*   h_b     = (bf16*)(ws + 8388608);     // 8 MiB (LN1 out; o_b aliases)
  ushort* o_b     = (ushort*)h_b;              // alias: h dead after GEMM1
  ushort* qkvb    = (ushort*)(ws + 16777216);  // 24 MiB: q/k/v bf16 [bh][s][64]
  ushort* q_b     = qkvb;
  ushort* k_b     = qkvb + 4194304;
  ushort* v_b     = qkvb + 8388608;
  float*  xnew    = (float*)(ws + 41943040);   // 16 MiB
  ushort* vt_b    = (ushort*)(ws + 58720256);  // 8 MiB: V^T [bh][dh][s]
  // total ws use: 64 MiB

  float* out  = (float*)d_out;
  float* rlog = out + (size_t)T_DIM * D_DIM;

  prep_kernel<<<8192, 256, 0, stream>>>(x, ln1w, ln1b, h_b,
                                        win, w_in_b, wout, w_out_b);
  gemm_qkv<<<dim3(QKV_N / 128, T_DIM / 128), 256, 0, stream>>>(
      h_b, w_in_b, bin, qkvb, D_DIM);
  transpose_v<<<1024, 256, 0, stream>>>(v_b, vt_b);
  attn_mfma<<<512, 512, 0, stream>>>(q_b, k_b, vt_b, o_b);
  gemm_out<<<dim3(D_DIM / 64, T_DIM / 128), 256, 0, stream>>>(
      (const bf16*)o_b, w_out_b, bout, x, xnew);
  final_kernel<<<T_DIM, 256, 0, stream>>>(xnew, ln2w, ln2b, gw, out, rlog);
}

// Round 9
// 113.607 us; speedup vs baseline: 1.3029x; 1.0165x over previous
//
#include <hip/hip_runtime.h>
#include <hip/hip_bf16.h>

#define S_DIM 1024
#define B_DIM 4
#define D_DIM 1024
#define H_DIM 16
#define DH    64
#define T_DIM (S_DIM * B_DIM)   // 4096
#define QKV_N (3 * D_DIM)       // 3072

using bf16 = __hip_bfloat16;
typedef __attribute__((ext_vector_type(4))) float fx4;
typedef __attribute__((ext_vector_type(8))) short bx8;

__device__ __forceinline__ unsigned short f2bf(float f) {
  union { float f; unsigned int u; } cv; cv.f = f;
  unsigned int u = cv.u;
  unsigned int r = (u + 0x7FFFu + ((u >> 16) & 1u)) >> 16;  // RNE
  return (unsigned short)r;
}

__device__ __forceinline__ void g2l16(const void* g, void* l) {
  __builtin_amdgcn_global_load_lds(
      (const __attribute__((address_space(1))) unsigned int*)g,
      (__attribute__((address_space(3))) unsigned int*)l, 16, 0, 0);
}

// ---------------- prep: LN1->bf16 (blocks 0..4095) + weight casts ----------
__global__ __launch_bounds__(256) void prep_kernel(
    const float* __restrict__ x, const float* __restrict__ w,
    const float* __restrict__ bb, bf16* __restrict__ out,
    const float* __restrict__ win, bf16* __restrict__ winb,
    const float* __restrict__ wout, bf16* __restrict__ woutb) {
  const int blk = blockIdx.x, tid = threadIdx.x;
  if (blk >= 4096) {  // weight cast: 1048576 fx4 chunks total
    const int i = (blk - 4096) * 256 + tid;
    const float* src; bf16* dst; int j;
    if (i < 786432) { src = win; dst = winb; j = i; }
    else { src = wout; dst = woutb; j = i - 786432; }
    const fx4 v = ((const fx4*)src)[j];
    ushort4 u;
    u.x = f2bf(v[0]); u.y = f2bf(v[1]); u.z = f2bf(v[2]); u.w = f2bf(v[3]);
    ((ushort4*)dst)[j] = u;
    return;
  }
  const int t = blk;
  const fx4 v = ((const fx4*)(x + (size_t)t * D_DIM))[tid];
  float s  = v[0] + v[1] + v[2] + v[3];
  float ss = v[0]*v[0] + v[1]*v[1] + v[2]*v[2] + v[3]*v[3];
#pragma unroll
  for (int off = 32; off >= 1; off >>= 1) {
    s  += __shfl_xor(s, off);
    ss += __shfl_xor(ss, off);
  }
  __shared__ float red[8];
  const int wid = tid >> 6, lane = tid & 63;
  if (lane == 0) { red[wid] = s; red[4 + wid] = ss; }
  __syncthreads();
  s  = red[0] + red[1] + red[2] + red[3];
  ss = red[4] + red[5] + red[6] + red[7];
  const float mu = s * (1.f / D_DIM);
  const float rstd = rsqrtf(ss * (1.f / D_DIM) - mu * mu + 1e-5f);
  const fx4 wv = ((const fx4*)w)[tid];
  const fx4 bv = ((const fx4*)bb)[tid];
  ushort4 u;
  u.x = f2bf((v[0] - mu) * rstd * wv[0] + bv[0]);
  u.y = f2bf((v[1] - mu) * rstd * wv[1] + bv[1]);
  u.z = f2bf((v[2] - mu) * rstd * wv[2] + bv[2]);
  u.w = f2bf((v[3] - mu) * rstd * wv[3] + bv[3]);
  ((ushort4*)(out + (size_t)t * D_DIM))[tid] = u;
}

// ---------------- qkv GEMM: 128x128, 3-deep pipeline, counted vmcnt --------
// LDS [128 rows][4 chunks of 16B], chunk swizzle c' = c ^ ((row>>1)&3):
// source permuted within each 64B row (coalescing kept), read uses the same
// involution -> 16 lanes hit all 8 bank-slots = conflict-free ds_read_b128.
// Pipeline ledger (4 loads/thread/tile): prologue stages t0,t1 (8 out).
// iter ki: stage(ki+2) -> 12; vmcnt(8) => ki landed; barrier; compute(ki);
// barrier (WAR: buf[(ki+3)%3]=buf[ki%3] restaged next iter). Tail: 4/0.
// qkv split-write bf16 [bh][s][64]; q pre-scaled by 0.125*log2(e).
__global__ __launch_bounds__(256, 2) void gemm_qkv(
    const bf16* __restrict__ A, const bf16* __restrict__ B,
    const float* __restrict__ bias, ushort* __restrict__ qkvb, int K) {
  __shared__ char sA[3][8192];
  __shared__ char sB[3][8192];
  const int tid  = threadIdx.x;
  const int brow = blockIdx.y * 128;
  const int bcol = blockIdx.x * 128;
  const int wid  = tid >> 6;
  const int lane = tid & 63;
  const int wr   = wid >> 1;
  const int wc   = wid & 1;
  const int fr   = lane & 15;
  const int fk   = lane >> 4;

  fx4 acc[4][4];
#pragma unroll
  for (int i = 0; i < 4; ++i)
#pragma unroll
    for (int j = 0; j < 4; ++j) acc[i][j] = 0.f;

  const int arow = tid >> 2;                    // 0..63
  const int gch  = (tid & 3) ^ ((arow >> 1) & 3);  // global chunk for this lane

  auto stage = [&](int buf, int kt) {
#pragma unroll
    for (int is = 0; is < 2; ++is) {
      const int row = is * 64 + arow;
      g2l16(A + (size_t)(brow + row) * K + kt + gch * 8,
            sA[buf] + is * 4096 + tid * 16);
      g2l16(B + (size_t)(bcol + row) * K + kt + gch * 8,
            sB[buf] + is * 4096 + tid * 16);
    }
  };

  stage(0, 0);
  stage(1, 32);

  const int nk = K >> 5;   // 32
#pragma unroll 1
  for (int ki = 0; ki < nk; ++ki) {
    const int buf = ki % 3;
    if (ki + 2 < nk) {
      stage((ki + 2) % 3, (ki + 2) * 32);
      asm volatile("s_waitcnt vmcnt(8)" ::: "memory");   // tile ki landed
    } else if (ki + 1 < nk) {
      asm volatile("s_waitcnt vmcnt(4)" ::: "memory");
    } else {
      asm volatile("s_waitcnt vmcnt(0)" ::: "memory");
    }
    __builtin_amdgcn_s_barrier();
    asm volatile("" ::: "memory");

    bx8 af[4], bfr[4];
#pragma unroll
    for (int mm = 0; mm < 4; ++mm) {
      const int ar = wr * 64 + mm * 16 + fr;
      af[mm] = *(const bx8*)(sA[buf] + ar * 64 + ((fk ^ ((ar >> 1) & 3)) << 4));
    }
#pragma unroll
    for (int nn = 0; nn < 4; ++nn) {
      const int br = wc * 64 + nn * 16 + fr;
      bfr[nn] = *(const bx8*)(sB[buf] + br * 64 + ((fk ^ ((br >> 1) & 3)) << 4));
    }
    __builtin_amdgcn_s_setprio(1);
#pragma unroll
    for (int mm = 0; mm < 4; ++mm)
#pragma unroll
      for (int nn = 0; nn < 4; ++nn)
        acc[mm][nn] = __builtin_amdgcn_mfma_f32_16x16x32_bf16(
            af[mm], bfr[nn], acc[mm][nn], 0, 0, 0);
    __builtin_amdgcn_s_setprio(0);

    asm volatile("" ::: "memory");
    __builtin_amdgcn_s_barrier();   // buf readers done before restage
    asm volatile("" ::: "memory");
  }

  // C/D layout: col = lane&15, row = (lane>>4)*4 + reg
  const int row0 = brow + wr * 64 + fk * 4;
  const int col0 = bcol + wc * 64 + fr;
#pragma unroll
  for (int mm = 0; mm < 4; ++mm) {
#pragma unroll
    for (int nn = 0; nn < 4; ++nn) {
      const int col = col0 + nn * 16;
      const float bv = bias[col];
      const int which = col >> 10;          // 0=q 1=k 2=v
      const int rem   = col & 1023;
      const int hh    = rem >> 6;
      const int dh    = rem & 63;
      // q scaled by DH^-0.5 * log2(e): softmax runs in exp2 domain
      const float scale = (which == 0) ? 0.18033688f : 1.0f;
#pragma unroll
      for (int rr = 0; rr < 4; ++rr) {
        const int row = row0 + mm * 16 + rr;  // t = s*B + b
        const int ss2 = row >> 2, bb2 = row & 3;
        const float v = (acc[mm][nn][rr] + bv) * scale;
        qkvb[(size_t)which * 4194304 +
             ((size_t)(bb2 * 16 + hh)) * 65536 + (size_t)ss2 * 64 + dh] = f2bf(v);
      }
    }
  }
}

// ---------------- V [bh][s][64] -> V^T [bh][dh][1024] ----------------
__global__ __launch_bounds__(256) void transpose_v(
    const ushort* __restrict__ v, ushort* __restrict__ vt) {
  __shared__ ushort tile[64][65];
  const int g  = blockIdx.x;
  const int bh = g >> 4, st = g & 15;
  const int s0 = st * 64;
  const int tid = threadIdx.x;
  const int r  = tid >> 2;          // 0..63
  const int c0 = (tid & 3) * 16;    // 0,16,32,48
  const ushort* src = v + (size_t)bh * 65536 + (size_t)(s0 + r) * 64 + c0;
#pragma unroll
  for (int i = 0; i < 2; ++i) {
    const bx8 d = *(const bx8*)(src + i * 8);
#pragma unroll
    for (int j = 0; j < 8; ++j) tile[r][c0 + i * 8 + j] = (ushort)d[j];
  }
  __syncthreads();
  ushort* dst = vt + (size_t)bh * 65536 + (size_t)r * 1024 + s0 + c0;
  bx8 w0, w1;
#pragma unroll
  for (int j = 0; j < 8; ++j) {
    w0[j] = (short)tile[c0 + j][r];
    w1[j] = (short)tile[c0 + 8 + j][r];
  }
  *(bx8*)dst = w0;
  *(bx8*)(dst + 8) = w1;
}

// ---------------- MFMA flash attention: 2 q-tiles share K/V staging --------
// 512-thread block: waves 0-3 own q-tile pr, waves 4-7 own 15-pr (uniform
// 17 compute-iters/block). One K/VT stage per iter serves both tiles.
// Grid 512 = whole grid resident, 2 blocks/CU; bid&7 = bh&7 keeps each bh's
// K/V on one XCD L2. Swapped S^T = mfma(K,Q); exp2-domain softmax;
// truncating bf16 P-pack; 2-phase counted-vmcnt pipeline; defer-max; setprio.
__global__ __launch_bounds__(512, 4) void attn_mfma(
    const ushort* __restrict__ qb, const ushort* __restrict__ kb,
    const ushort* __restrict__ vtb, ushort* __restrict__ ob) {
  __shared__ __align__(16) char sK[2][8192];
  __shared__ __align__(16) char sVT[2][8192];
  __shared__ __align__(16) char sP[16384];
  const int tid  = threadIdx.x;
  const int wid  = tid >> 6;        // 0..7
  const int lane = tid & 63;
  const int bid  = blockIdx.x;
  const int xcd  = bid & 7;
  const int r2   = bid >> 3;        // 0..63
  const int pr   = r2 & 7;
  const int bh   = (r2 >> 3) * 8 + xcd;
  const int b    = bh >> 4, h = bh & 15;
  const int fr   = lane & 15;
  const int fk   = lane >> 4;
  const size_t bhoff = (size_t)bh * 65536;
  char* const sPw = sP + wid * 2048;
  const int swp = (fr & 7) << 4;
  const int qt_max  = 15 - pr;
  const int qt_mine = (wid < 4) ? pr : qt_max;
  const int wid4 = wid & 3;

  auto stage = [&](int buf, int k0) {
    const int L    = tid * 16;
    const int row  = L >> 7;
    const int colb = (L & 127) ^ ((row & 7) << 4);
    g2l16(kb  + bhoff + (size_t)(k0 + row) * 64 + (colb >> 1), sK[buf]  + L);
    g2l16(vtb + bhoff + (size_t)row * 1024 + k0 + (colb >> 1), sVT[buf] + L);
  };

  const int q0w = qt_mine * 64 + wid4 * 16;
  const ushort* qp = qb + bhoff + (size_t)(q0w + fr) * 64;
  const bx8 qf0 = *(const bx8*)(qp + fk * 8);
  const bx8 qf1 = *(const bx8*)(qp + 32 + fk * 8);
  asm volatile("s_waitcnt vmcnt(0)" ::: "memory");  // exact vmcnt counting

  fx4 o4[4];
  float m = -3e38f, l = 0.f;
#pragma unroll
  for (int dt = 0; dt < 4; ++dt) o4[dt] = 0.f;

  stage(0, 0);   // 2 loads/thread outstanding

#pragma unroll 1
  for (int kbk = 0; kbk <= qt_max; ++kbk) {
    const int cur = kbk & 1;
    if (kbk < qt_max) {
      stage(cur ^ 1, (kbk + 1) * 64);                   // +2 -> 4 outstanding
      asm volatile("s_waitcnt vmcnt(2)" ::: "memory");  // cur's 2 landed
    } else {
      asm volatile("s_waitcnt vmcnt(0)" ::: "memory");
    }
    __builtin_amdgcn_s_barrier();
    asm volatile("" ::: "memory");

    if (kbk <= qt_mine) {   // wave-uniform guard; no barriers inside
      const char* sKc  = sK[cur];
      const char* sVTc = sVT[cur];

      // --- S^T = mfma(K, Q): s4[kt][rr] = S[key=kt*16+fk*4+rr][q=fr] ---
      fx4 s4[4];
      __builtin_amdgcn_s_setprio(1);
#pragma unroll
      for (int kt = 0; kt < 4; ++kt) {
        const int krow = kt * 16 + fr;
        const int sw   = (krow & 7) << 4;
        const bx8 kf0 = *(const bx8*)(sKc + krow * 128 + ((fk * 16) ^ sw));
        const bx8 kf1 = *(const bx8*)(sKc + krow * 128 + ((64 + fk * 16) ^ sw));
        fx4 z = {0.f, 0.f, 0.f, 0.f};
        z = __builtin_amdgcn_mfma_f32_16x16x32_bf16(kf0, qf0, z, 0, 0, 0);
        s4[kt] = __builtin_amdgcn_mfma_f32_16x16x32_bf16(kf1, qf1, z, 0, 0, 0);
      }
      __builtin_amdgcn_s_setprio(0);

      if (kbk == qt_mine) {  // diagonal: wave-relative causal mask
        const int qloc = wid4 * 16 + fr;
#pragma unroll
        for (int kt = 0; kt < 4; ++kt) {
          const int keyb = kt * 16 + fk * 4;
#pragma unroll
          for (int rr = 0; rr < 4; ++rr)
            if (keyb + rr > qloc) s4[kt][rr] = -3e38f;
        }
      }

      // --- online softmax in exp2 domain: lane owns q=fr ---
      float pm = s4[0][0];
#pragma unroll
      for (int kt = 0; kt < 4; ++kt)
#pragma unroll
        for (int rr = 0; rr < 4; ++rr) pm = fmaxf(pm, s4[kt][rr]);
      pm = fmaxf(pm, __shfl_xor(pm, 16));
      pm = fmaxf(pm, __shfl_xor(pm, 32));

      if (__any(pm > m + 11.5f)) {   // defer-max (T13)
        const float mn = fmaxf(m, pm);
        const float f  = exp2f(m - mn);
        m = mn;
        l *= f;
        float fq[4];
#pragma unroll
        for (int rr = 0; rr < 4; ++rr) fq[rr] = __shfl(f, fk * 4 + rr);
#pragma unroll
        for (int dt = 0; dt < 4; ++dt)
#pragma unroll
          for (int rr = 0; rr < 4; ++rr) o4[dt][rr] *= fq[rr];
      }

      // --- P = exp2(S-m), truncating bf16 pack, b64 LDS writes ---
#pragma unroll
      for (int kt = 0; kt < 4; ++kt) {
        union { float f; unsigned u; } a0, a1, a2, a3;
        a0.f = exp2f(s4[kt][0] - m);
        a1.f = exp2f(s4[kt][1] - m);
        a2.f = exp2f(s4[kt][2] - m);
        a3.f = exp2f(s4[kt][3] - m);
        l += (a0.f + a1.f) + (a2.f + a3.f);
        uint2 pk;
        pk.x = (a0.u >> 16) | (a1.u & 0xFFFF0000u);
        pk.y = (a2.u >> 16) | (a3.u & 0xFFFF0000u);
        *(uint2*)(sPw + ((fr * 128 + kt * 32 + fk * 8) ^ swp)) = pk;
      }

      // --- O += P V ---
      __builtin_amdgcn_s_setprio(1);
#pragma unroll
      for (int c = 0; c < 2; ++c) {
        const bx8 pa = *(const bx8*)(sPw + ((fr * 128 + c * 64 + fk * 16) ^ swp));
#pragma unroll
        for (int dt = 0; dt < 4; ++dt) {
          const int vrow = dt * 16 + fr;
          const bx8 vf = *(const bx8*)(sVTc + vrow * 128 +
                                       ((c * 64 + fk * 16) ^ ((vrow & 7) << 4)));
          o4[dt] = __builtin_amdgcn_mfma_f32_16x16x32_bf16(pa, vf, o4[dt], 0, 0, 0);
        }
      }
      __builtin_amdgcn_s_setprio(0);
    }

    asm volatile("" ::: "memory");
    __builtin_amdgcn_s_barrier();   // readers done before next overwrite
    asm volatile("" ::: "memory");
  }

  // --- epilogue: total row sums, per-output-row norms, store ---
  l += __shfl_xor(l, 16);
  l += __shfl_xor(l, 32);
  const float linv = 1.f / l;
  float lq[4];
#pragma unroll
  for (int rr = 0; rr < 4; ++rr) lq[rr] = __shfl(linv, fk * 4 + rr);

#pragma unroll
  for (int dt = 0; dt < 4; ++dt) {
#pragma unroll
    for (int rr = 0; rr < 4; ++rr) {
      const int qq = q0w + fk * 4 + rr;
      ob[((size_t)qq * 4 + b) * 1024 + h * 64 + dt * 16 + fr] =
          f2bf(o4[dt][rr] * lq[rr]);
    }
  }
}

// ---------------- out-proj GEMM: 128x64, 3-deep pipeline, swizzled ---------
// C(fp32)[4096,1024] = A[4096,1024] @ B[1024,1024]^T + bias + resid.
// Same chunk swizzle + counted-vmcnt ledger (3 loads/thread/tile):
// prologue 6 out; iter: stage(+3)->9; vmcnt(6); tail 3/0.
__global__ __launch_bounds__(256, 2) void gemm_out(
    const bf16* __restrict__ A, const bf16* __restrict__ B,
    const float* __restrict__ bias, const float* __restrict__ resid,
    float* __restrict__ C) {
  __shared__ char sA[3][8192];
  __shared__ char sB[3][4096];
  const int tid  = threadIdx.x;
  const int brow = blockIdx.y * 128;
  const int bcol = blockIdx.x * 64;
  const int wid  = tid >> 6;
  const int lane = tid & 63;
  const int wr   = wid >> 1;      // 0..1: 64-row stripe
  const int wc   = wid & 1;       // 0..1: 32-col stripe
  const int fr   = lane & 15;
  const int fk   = lane >> 4;

  fx4 acc[4][2];
#pragma unroll
  for (int i = 0; i < 4; ++i)
#pragma unroll
    for (int j = 0; j < 2; ++j) acc[i][j] = 0.f;

  const int arow = tid >> 2;
  const int gch  = (tid & 3) ^ ((arow >> 1) & 3);

  auto stage = [&](int buf, int kt) {
#pragma unroll
    for (int is = 0; is < 2; ++is) {
      const int row = is * 64 + arow;
      g2l16(A + (size_t)(brow + row) * 1024 + kt + gch * 8,
            sA[buf] + is * 4096 + tid * 16);
    }
    g2l16(B + (size_t)(bcol + arow) * 1024 + kt + gch * 8,
          sB[buf] + tid * 16);
  };

  stage(0, 0);
  stage(1, 32);

#pragma unroll 1
  for (int ki = 0; ki < 32; ++ki) {
    const int buf = ki % 3;
    if (ki + 2 < 32) {
      stage((ki + 2) % 3, (ki + 2) * 32);
      asm volatile("s_waitcnt vmcnt(6)" ::: "memory");
    } else if (ki + 1 < 32) {
      asm volatile("s_waitcnt vmcnt(3)" ::: "memory");
    } else {
      asm volatile("s_waitcnt vmcnt(0)" ::: "memory");
    }
    __builtin_amdgcn_s_barrier();
    asm volatile("" ::: "memory");

    bx8 af[4], bfr[2];
#pragma unroll
    for (int mm = 0; mm < 4; ++mm) {
      const int ar = wr * 64 + mm * 16 + fr;
      af[mm] = *(const bx8*)(sA[buf] + ar * 64 + ((fk ^ ((ar >> 1) & 3)) << 4));
    }
#pragma unroll
    for (int nn = 0; nn < 2; ++nn) {
      const int br = wc * 32 + nn * 16 + fr;
      bfr[nn] = *(const bx8*)(sB[buf] + br * 64 + ((fk ^ ((br >> 1) & 3)) << 4));
    }
    __builtin_amdgcn_s_setprio(1);
#pragma unroll
    for (int mm = 0; mm < 4; ++mm)
#pragma unroll
      for (int nn = 0; nn < 2; ++nn)
        acc[mm][nn] = __builtin_amdgcn_mfma_f32_16x16x32_bf16(
            af[mm], bfr[nn], acc[mm][nn], 0, 0, 0);
    __builtin_amdgcn_s_setprio(0);

    asm volatile("" ::: "memory");
    __builtin_amdgcn_s_barrier();
    asm volatile("" ::: "memory");
  }

  const int row0 = brow + wr * 64 + fk * 4;
  const int col0 = bcol + wc * 32 + fr;
#pragma unroll
  for (int mm = 0; mm < 4; ++mm) {
#pragma unroll
    for (int nn = 0; nn < 2; ++nn) {
      const int col = col0 + nn * 16;
      const float bv = bias[col];
#pragma unroll
      for (int rr = 0; rr < 4; ++rr) {
        const int row = row0 + mm * 16 + rr;
        C[(size_t)row * 1024 + col] =
            acc[mm][nn][rr] + bv + resid[(size_t)row * 1024 + col];
      }
    }
  }
}

// ---------------- LN2 + router + gate + final multiply ----------------
__global__ __launch_bounds__(256) void final_kernel(
    const float* __restrict__ xn, const float* __restrict__ w,
    const float* __restrict__ bb, const float* __restrict__ gw,
    float* __restrict__ out, float* __restrict__ rlog) {
  const int t = blockIdx.x, tid = threadIdx.x;
  const fx4 v = ((const fx4*)(xn + (size_t)t * D_DIM))[tid];
  float s  = v[0] + v[1] + v[2] + v[3];
  float ss = v[0]*v[0] + v[1]*v[1] + v[2]*v[2] + v[3]*v[3];
#pragma unroll
  for (int off = 32; off >= 1; off >>= 1) {
    s  += __shfl_xor(s, off);
    ss += __shfl_xor(ss, off);
  }
  __shared__ float red[8];
  __shared__ float red2[12];
  const int wid = tid >> 6, lane = tid & 63;
  if (lane == 0) { red[wid] = s; red[4 + wid] = ss; }
  __syncthreads();
  s  = red[0] + red[1] + red[2] + red[3];
  ss = red[4] + red[5] + red[6] + red[7];
  const float mu = s * (1.f / D_DIM);
  const float rstd = rsqrtf(ss * (1.f / D_DIM) - mu * mu + 1e-5f);
  const fx4 wv = ((const fx4*)w)[tid];
  const fx4 bv = ((const fx4*)bb)[tid];
  fx4 hv;
#pragma unroll
  for (int cc = 0; cc < 4; ++cc) hv[cc] = (v[cc] - mu) * rstd * wv[cc] + bv[cc];

  const fx4 w0 = ((const fx4*)(gw           ))[tid];
  const fx4 w1 = ((const fx4*)(gw +     D_DIM))[tid];
  const fx4 w2 = ((const fx4*)(gw + 2 * D_DIM))[tid];
  float g0 = hv[0]*w0[0] + hv[1]*w0[1] + hv[2]*w0[2] + hv[3]*w0[3];
  float g1 = hv[0]*w1[0] + hv[1]*w1[1] + hv[2]*w1[2] + hv[3]*w1[3];
  float g2 = hv[0]*w2[0] + hv[1]*w2[1] + hv[2]*w2[2] + hv[3]*w2[3];
#pragma unroll
  for (int off = 32; off >= 1; off >>= 1) {
    g0 += __shfl_xor(g0, off);
    g1 += __shfl_xor(g1, off);
    g2 += __shfl_xor(g2, off);
  }
  if (lane == 0) { red2[wid] = g0; red2[4 + wid] = g1; red2[8 + wid] = g2; }
  __syncthreads();
  g0 = red2[0] + red2[1] + red2[2]  + red2[3];
  g1 = red2[4] + red2[5] + red2[6]  + red2[7];
  g2 = red2[8] + red2[9] + red2[10] + red2[11];

  // gate = pmax/(pmax+p2nd) of softmax over 3 = 1/(1+exp(l_mid - l_max))
  const float lmax = fmaxf(g0, fmaxf(g1, g2));
  const float lmin = fminf(g0, fminf(g1, g2));
  const float lmid = (g0 + g1 + g2) - lmax - lmin;
  const float gate = 1.f / (1.f + __expf(lmid - lmax));

  ((fx4*)(out + (size_t)t * D_DIM))[tid] = v * gate;
  if (tid == 0) {
    rlog[(size_t)t * 3 + 0] = g0;
    rlog[(size_t)t * 3 + 1] = g1;
    rlog[(size_t)t * 3 + 2] = g2;
  }
}

extern "C" void kernel_launch(void* const* d_in, const int* in_sizes, int n_in,
                              void* d_out, int out_size, void* d_ws, size_t ws_size,
                              hipStream_t stream) {
  (void)in_sizes; (void)n_in; (void)out_size; (void)ws_size;
  const float* x    = (const float*)d_in[0];
  const float* ln1w = (const float*)d_in[1];
  const float* ln1b = (const float*)d_in[2];
  const float* ln2w = (const float*)d_in[3];
  const float* ln2b = (const float*)d_in[4];
  const float* win  = (const float*)d_in[5];
  const float* bin  = (const float*)d_in[6];
  const float* wout = (const float*)d_in[7];
  const float* bout = (const float*)d_in[8];
  const float* gw   = (const float*)d_in[9];
  // fc_w / fc_b / proj_w / proj_b (d_in[10..13]) are dead code in the reference.

  char* ws = (char*)d_ws;
  bf16*   w_in_b  = (bf16*)(ws);               // 6 MiB
  bf16*   w_out_b = (bf16*)(ws + 6291456);     // 2 MiB
  bf16*   h_b     = (bf16*)(ws + 8388608);     // 8 MiB (LN1 out; o_b aliases)
  ushort* o_b     = (ushort*)h_b;              // alias: h dead after GEMM1
  ushort* qkvb    = (ushort*)(ws + 16777216);  // 24 MiB: q/k/v bf16 [bh][s][64]
  ushort* q_b     = qkvb;
  ushort* k_b     = qkvb + 4194304;
  ushort* v_b     = qkvb + 8388608;
  float*  xnew    = (float*)(ws + 41943040);   // 16 MiB
  ushort* vt_b    = (ushort*)(ws + 58720256);  // 8 MiB: V^T [bh][dh][s]
  // total ws use: 64 MiB

  float* out  = (float*)d_out;
  float* rlog = out + (size_t)T_DIM * D_DIM;

  prep_kernel<<<8192, 256, 0, stream>>>(x, ln1w, ln1b, h_b,
                                        win, w_in_b, wout, w_out_b);
  gemm_qkv<<<dim3(QKV_N / 128, T_DIM / 128), 256, 0, stream>>>(
      h_b, w_in_b, bin, qkvb, D_DIM);
  transpose_v<<<1024, 256, 0, stream>>>(v_b, vt_b);
  attn_mfma<<<512, 512, 0, stream>>>(q_b, k_b, vt_b, o_b);
  gemm_out<<<dim3(D_DIM / 64, T_DIM / 128), 256, 0, stream>>>(
      (const bf16*)o_b, w_out_b, bout, x, xnew);
  final_kernel<<<T_DIM, 256, 0, stream>>>(xnew, ln2w, ln2b, gw, out, rlog);
}